// Round 3
// baseline (622.346 us; speedup 1.0000x reference)
//
#include <hip/hip_runtime.h>
#include <hip/hip_bf16.h>
#include <hip/hip_fp16.h>

typedef unsigned short u16;
typedef unsigned int u32;

#define N_NODES 100000
#define N_EDGES 600000
#define FIN_D   256
#define HDIM    128
#define NCLS    47
#define NOUT_D  10000
#define NCHUNK  196          // ceil(N_NODES/512)
#define NP2     100352       // NCHUNK*512, padded node count
#define PCH     4096         // edges per partition block
#define PNB     ((N_EDGES + PCH - 1) / PCH)   // 147

typedef short bf16x8 __attribute__((ext_vector_type(8)));
typedef float f32x4  __attribute__((ext_vector_type(4)));

__device__ __forceinline__ float bf2f(u16 u) {
    union { u32 i; float f; } v; v.i = ((u32)u) << 16; return v.f;
}
__device__ __forceinline__ u16 f2bf(float f) {
    __hip_bfloat16 h = __float2bfloat16(f);
    return *reinterpret_cast<u16*>(&h);
}
__device__ __forceinline__ float loadF(const void* p, size_t i, bool f32) {
    if (f32) return ((const float*)p)[i];
    return bf2f(((const u16*)p)[i]);
}
__device__ __forceinline__ float wave_sum(float v) {
    #pragma unroll
    for (int o = 32; o > 0; o >>= 1) v += __shfl_xor(v, o, 64);
    return v;
}
__device__ __forceinline__ float wave_max(float v) {
    #pragma unroll
    for (int o = 32; o > 0; o >>= 1) v = fmaxf(v, __shfl_xor(v, o, 64));
    return v;
}
__device__ __forceinline__ int wave_sum_i(int v) {
    #pragma unroll
    for (int o = 32; o > 0; o >>= 1) v += __shfl_xor(v, o, 64);
    return v;
}
__device__ __forceinline__ int block_excl_scan_256(int v, int* wsum) {
    int lane = threadIdx.x & 63, wv = threadIdx.x >> 6;
    int inc = v;
    #pragma unroll
    for (int off = 1; off < 64; off <<= 1) {
        int u = __shfl_up(inc, off, 64);
        if (lane >= off) inc += u;
    }
    if (lane == 63) wsum[wv] = inc;
    __syncthreads();
    if (threadIdx.x == 0) {
        int a = 0;
        #pragma unroll
        for (int w = 0; w < 4; ++w) { int t = wsum[w]; wsum[w] = a; a += t; }
    }
    __syncthreads();
    return inc - v + wsum[wv];
}

// ---------------- dtype detector ---------------------------------------
__global__ __launch_bounds__(256) void dtype_detect_kernel(
    const u16* __restrict__ x, int* __restrict__ flag)
{
    __shared__ int cnt;
    if (threadIdx.x == 0) cnt = 0;
    __syncthreads();
    int local = 0;
    for (int i = threadIdx.x; i < 65536; i += 256) {
        u32 e = (x[i] >> 7) & 0xFF;
        if (e >= 200) local++;
    }
    atomicAdd(&cnt, local);
    __syncthreads();
    if (threadIdx.x == 0) *flag = (cnt > 16) ? 1 : 0;
}

// ---------------- CSR build (both edge lists per dispatch) --------------
__global__ __launch_bounds__(256) void hist2_kernel(
    const int* __restrict__ dst, int* __restrict__ deg2, int egrid)
{
    int half = (blockIdx.x >= egrid) ? 1 : 0;
    int e = (blockIdx.x - half * egrid) * 256 + threadIdx.x;
    if (e < N_EDGES) atomicAdd(&deg2[half * NP2 + dst[half * N_EDGES + e]], 1);
}

__global__ __launch_bounds__(256) void csum2_kernel(
    const int* __restrict__ deg2, int* __restrict__ csum)
{
    __shared__ int ws[4];
    int half = (blockIdx.x >= NCHUNK) ? 1 : 0;
    int b = blockIdx.x - half * NCHUNK;
    int i0 = half * NP2 + b * 512 + threadIdx.x;
    int v = 0;
    if (b * 512 + threadIdx.x < N_NODES) v += deg2[i0];
    if (b * 512 + threadIdx.x + 256 < N_NODES) v += deg2[i0 + 256];
    v = wave_sum_i(v);
    int lane = threadIdx.x & 63, wv = threadIdx.x >> 6;
    if (lane == 0) ws[wv] = v;
    __syncthreads();
    if (threadIdx.x == 0)
        csum[blockIdx.x] = ws[0] + ws[1] + ws[2] + ws[3];
}

// exclusive-scan per-bucket counts; coff compact, bcur padded 1/cacheline.
__global__ __launch_bounds__(256) void coff2_kernel(
    const int* __restrict__ csum, int* __restrict__ coff,
    int* __restrict__ bcur)
{
    __shared__ int wsum[4];
    int t = threadIdx.x;
    for (int h = 0; h < 2; ++h) {
        int v = (t < NCHUNK) ? csum[h * NCHUNK + t] : 0;
        int excl = block_excl_scan_256(v, wsum);
        if (t < NCHUNK) {
            coff[h * NCHUNK + t] = excl;
            bcur[(h * NCHUNK + t) * 16] = excl;   // 64B-padded cursor
        }
        __syncthreads();
    }
}

__global__ __launch_bounds__(256) void scan2_kernel(
    const int* __restrict__ deg2, const int* __restrict__ coff,
    int* __restrict__ rp0, int* __restrict__ rp1)
{
    __shared__ int wsum[4];
    int half = (blockIdx.x >= NCHUNK) ? 1 : 0;
    int b = blockIdx.x - half * NCHUNK;
    const int* deg = deg2 + half * NP2;
    int* rp = half ? rp1 : rp0;
    int t = threadIdx.x;
    int i0 = b * 512 + 2 * t;
    int d0 = (i0 < N_NODES) ? deg[i0] : 0;
    int d1 = (i0 + 1 < N_NODES) ? deg[i0 + 1] : 0;
    int excl = block_excl_scan_256(d0 + d1, wsum);
    int base = coff[half * NCHUNK + b] + excl;
    if (i0 < N_NODES)     rp[i0] = base;
    if (i0 + 1 < N_NODES) rp[i0 + 1] = base + d0;
    if (b == 0 && t == 0) rp[N_NODES] = N_EDGES;
}

// Pass 1: block-local radix partition. Each block takes 4096 edges, LDS
// histogram by bucket (dst>>9), ONE global atomic per (block,bucket) onto
// a cacheline-padded cursor, then contiguous per-bucket writes to tmp.
__global__ __launch_bounds__(256) void bucket_part_kernel(
    const int* __restrict__ src, const int* __restrict__ dst,
    const int* __restrict__ comp1,
    int* __restrict__ bcur, int2* __restrict__ tmp)
{
    __shared__ int hist[NCHUNK];
    __shared__ int base[NCHUNK];
    int half = (blockIdx.x >= PNB) ? 1 : 0;
    int b = blockIdx.x - half * PNB;
    int e0 = b * PCH;
    for (int i = threadIdx.x; i < NCHUNK; i += 256) hist[i] = 0;
    __syncthreads();

    int2 loc[16];
    #pragma unroll
    for (int t = 0; t < 16; ++t) {
        int e = e0 + t * 256 + threadIdx.x;
        loc[t].y = -1;
        if (e < N_EDGES) {
            int ge = half * N_EDGES + e;
            int d = dst[ge];
            int s = src[ge];
            if (half) s = comp1[s];
            loc[t] = make_int2(s, d);
            atomicAdd(&hist[d >> 9], 1);
        }
    }
    __syncthreads();
    for (int i = threadIdx.x; i < NCHUNK; i += 256) {
        int h = hist[i];
        base[i] = (h > 0) ? atomicAdd(&bcur[(half * NCHUNK + i) * 16], h) : 0;
        hist[i] = 0;      // reuse as block-local cursor
    }
    __syncthreads();
    #pragma unroll
    for (int t = 0; t < 16; ++t) {
        if (loc[t].y >= 0) {
            int bk = loc[t].y >> 9;
            int pos = base[bk] + atomicAdd(&hist[bk], 1);
            tmp[(size_t)half * N_EDGES + pos] = loc[t];
        }
    }
}

// Pass 2: one block per bucket; LDS cursors from rp; sequential read of the
// bucket's pairs, LDS-atomic rank, write into the bucket's contiguous
// output window of ei (L2-resident, written once).
__global__ __launch_bounds__(256) void bucket_sort_kernel(
    const int2* __restrict__ tmp,
    const int* __restrict__ rp0, const int* __restrict__ rp1,
    const int* __restrict__ coff, const int* __restrict__ csum,
    int* __restrict__ ei0, int* __restrict__ ei1)
{
    __shared__ int cur[512];
    int half = (blockIdx.x >= NCHUNK) ? 1 : 0;
    int b = blockIdx.x - half * NCHUNK;
    const int* rp = half ? rp1 : rp0;
    int* ei = half ? ei1 : ei0;
    int n0 = b * 512;
    #pragma unroll
    for (int i = threadIdx.x; i < 512; i += 256) {
        int n = n0 + i;
        cur[i] = (n < N_NODES) ? rp[n] : 0;
    }
    __syncthreads();
    int beg = coff[half * NCHUNK + b];
    int end = beg + csum[half * NCHUNK + b];
    for (int i = beg + threadIdx.x; i < end; i += 256) {
        int2 p = tmp[(size_t)half * N_EDGES + i];
        int pos = atomicAdd(&cur[p.y & 511], 1);
        ei[pos] = p.x;
    }
}

// ---------------- Weight pre-pack into MFMA B-fragment order -----------
__global__ __launch_bounds__(256) void pack_b_kernel(
    const void* __restrict__ enc_w, const void* __restrict__ gcn_w,
    const int* __restrict__ dt, u16* __restrict__ Bp)
{
    const bool f32 = (*dt != 0);
    int o = blockIdx.x * 256 + threadIdx.x;
    if (o >= 32768 + 3 * 16384) return;
    const void* srcp; size_t soff; int m;
    if (o < 32768) { srcp = enc_w; soff = 0; m = o; }
    else {
        int l = (o - 32768) >> 14;
        srcp = gcn_w; soff = (size_t)l * 16384; m = (o - 32768) & 16383;
    }
    int j    = m & 7;
    int lane = (m >> 3) & 63;
    int ct   = (m >> 9) & 7;
    int kidx = m >> 12;
    int k = kidx * 32 + (lane >> 4) * 8 + j;
    int n = ct * 16 + (lane & 15);
    Bp[o] = f2bf(loadF(srcp, soff + (size_t)k * HDIM + n, f32));
}

// ---------------- Encoder GEMM: HB0 = bf16(x @ enc_w + enc_b) ----------
// v4: structural fix. v2/v3 micro-scheduling was flat (62-67us, ~300cy per
// VMEM serialized): the 64 per-wave B-fragment GLOBAL loads were the chain
// and the compiler refuses to keep two register B-buffers live. So: B goes
// to LDS once per block (global_load_lds w=16, like conv_gemm which never
// shows in top-5), 256 rows/block (4x fewer blocks, B amortized 4x), and
// the only VMEM left is the A stream with a 3-buffer depth-2 rotation.
#define ELOADA(BUF, K)                                                         \
    { _Pragma("unroll")                                                        \
      for (int t = 0; t < 4; ++t)                                              \
          BUF[t] = *(const bf16x8*)(baseA[t] + (K) * 32); }

#define EK(K, B0, B1, B2)                                                      \
    {                                                                          \
        if ((K) + 2 < 8) ELOADA(B2, (K) + 2);                                  \
        bf16x8 bf[8];                                                          \
        _Pragma("unroll")                                                      \
        for (int ct = 0; ct < 8; ++ct)                                         \
            bf[ct] = *(const bf16x8*)(BshP + (K) * 4096 + ct * 512 + lane * 8);\
        __builtin_amdgcn_sched_barrier(0);                                     \
        _Pragma("unroll")                                                      \
        for (int t = 0; t < 4; ++t)                                            \
            _Pragma("unroll")                                                  \
            for (int ct = 0; ct < 8; ++ct)                                     \
                acc[t][ct] = __builtin_amdgcn_mfma_f32_16x16x32_bf16(          \
                    B0[t], bf[ct], acc[t][ct], 0, 0, 0);                       \
    }

#define ELOADF(BUF, K)                                                         \
    { _Pragma("unroll")                                                        \
      for (int t = 0; t < 4; ++t) {                                            \
          BUF[t][0] = *(const float4*)(baseAf[t] + (K) * 32);                  \
          BUF[t][1] = *(const float4*)(baseAf[t] + (K) * 32 + 4);              \
      } }

#define EKF(K, RC, RN)                                                         \
    {                                                                          \
        if ((K) + 1 < 8) ELOADF(RN, (K) + 1);                                  \
        bf16x8 av[4];                                                          \
        _Pragma("unroll")                                                      \
        for (int t = 0; t < 4; ++t) {                                          \
            union { u32 u[4]; bf16x8 v; } cv;                                  \
            cv.u[0] = (u32)f2bf(RC[t][0].x) | ((u32)f2bf(RC[t][0].y) << 16);   \
            cv.u[1] = (u32)f2bf(RC[t][0].z) | ((u32)f2bf(RC[t][0].w) << 16);   \
            cv.u[2] = (u32)f2bf(RC[t][1].x) | ((u32)f2bf(RC[t][1].y) << 16);   \
            cv.u[3] = (u32)f2bf(RC[t][1].z) | ((u32)f2bf(RC[t][1].w) << 16);   \
            av[t] = cv.v;                                                      \
        }                                                                      \
        bf16x8 bf[8];                                                          \
        _Pragma("unroll")                                                      \
        for (int ct = 0; ct < 8; ++ct)                                         \
            bf[ct] = *(const bf16x8*)(BshP + (K) * 4096 + ct * 512 + lane * 8);\
        __builtin_amdgcn_sched_barrier(0);                                     \
        _Pragma("unroll")                                                      \
        for (int t = 0; t < 4; ++t)                                            \
            _Pragma("unroll")                                                  \
            for (int ct = 0; ct < 8; ++ct)                                     \
                acc[t][ct] = __builtin_amdgcn_mfma_f32_16x16x32_bf16(          \
                    av[t], bf[ct], acc[t][ct], 0, 0, 0);                       \
    }

__global__ __launch_bounds__(256, 2) void enc_gemm_kernel(
    const void* __restrict__ Araw, const u16* __restrict__ Bp,
    const void* __restrict__ bias, const int* __restrict__ dt,
    u16* __restrict__ OutBF)
{
    __shared__ u16 Bsh[32768];                    // full 64KB encoder B
    const bool f32 = (*dt != 0);
    const int tid  = threadIdx.x;
    const int w    = tid >> 6;
    const int lane = tid & 63;
    const int quad = lane >> 4;
    const int cl   = lane & 15;
    const int m0   = blockIdx.x * 256;
    const u16* BshP = &Bsh[0];

    // ---- stage B: linear 64KB copy via global_load_lds (16B/lane) ----
    {
        const char* gB = (const char*)Bp;
        #pragma unroll
        for (int i = 0; i < 16; ++i) {
            size_t off = (size_t)w * 16384 + (size_t)i * 1024;
            __builtin_amdgcn_global_load_lds(
                (const __attribute__((address_space(1))) u32*)(gB + off + (size_t)lane * 16),
                (__attribute__((address_space(3))) u32*)((char*)&Bsh[0] + off),
                16, 0, 0);
        }
    }

    // row bases for this wave's 4 row-tiles (rows m0 + w*64 + t*16 + cl)
    int rows[4];
    #pragma unroll
    for (int t = 0; t < 4; ++t) {
        int r = m0 + w * 64 + t * 16 + cl;
        rows[t] = (r >= N_NODES) ? (N_NODES - 1) : r;
    }

    f32x4 acc[4][8];
    #pragma unroll
    for (int t = 0; t < 4; ++t)
        #pragma unroll
        for (int ct = 0; ct < 8; ++ct) acc[t][ct] = (f32x4){0.f, 0.f, 0.f, 0.f};

    __syncthreads();   // B staged (drains vmcnt incl. global_load_lds)

    if (!f32) {
        const u16* baseA[4];
        #pragma unroll
        for (int t = 0; t < 4; ++t)
            baseA[t] = (const u16*)Araw + (size_t)rows[t] * FIN_D + quad * 8;
        bf16x8 a0[4], a1[4], a2[4];
        ELOADA(a0, 0); ELOADA(a1, 1);
        EK(0, a0, a1, a2) EK(1, a1, a2, a0) EK(2, a2, a0, a1) EK(3, a0, a1, a2)
        EK(4, a1, a2, a0) EK(5, a2, a0, a1) EK(6, a0, a1, a2) EK(7, a1, a2, a0)
    } else {
        const float* baseAf[4];
        #pragma unroll
        for (int t = 0; t < 4; ++t)
            baseAf[t] = (const float*)Araw + (size_t)rows[t] * FIN_D + quad * 8;
        float4 f0[4][2], f1[4][2];
        ELOADF(f0, 0);
        EKF(0, f0, f1) EKF(1, f1, f0) EKF(2, f0, f1) EKF(3, f1, f0)
        EKF(4, f0, f1) EKF(5, f1, f0) EKF(6, f0, f1) EKF(7, f1, f0)
    }

    #pragma unroll
    for (int t = 0; t < 4; ++t) {
        #pragma unroll
        for (int reg = 0; reg < 4; ++reg) {
            int grow = m0 + w * 64 + t * 16 + quad * 4 + reg;
            if (grow >= N_NODES) continue;
            #pragma unroll
            for (int ct = 0; ct < 8; ++ct) {
                int col = ct * 16 + cl;
                float v = acc[t][ct][reg] + loadF(bias, col, f32);
                OutBF[(size_t)grow * HDIM + col] = f2bf(v);
            }
        }
    }
}

// ---------------- Softmax aggregation -> bf16 A-matrix -----------------
template<bool OWN_MAP>
__global__ __launch_bounds__(256) void agg_msg_kernel(
    const int* __restrict__ rp, const int* __restrict__ eidx,
    const u16* __restrict__ HBin, const int* __restrict__ own_map,
    u16* __restrict__ Amsg)
{
    int wave = threadIdx.x >> 6;
    int lane = threadIdx.x & 63;
    int n = blockIdx.x * 4 + wave;
    if (n >= N_NODES) return;
    const u32* HB32 = (const u32*)HBin;
    int nn = OWN_MAP ? own_map[n] : n;
    u32 own = HB32[(size_t)nn * 64 + lane];
    int beg = rp[n], end = rp[n + 1];
    float den0 = 0.f, den1 = 0.f, num0 = 0.f, num1 = 0.f;
    for (int j0 = beg; j0 < end; j0 += 8) {
        int cnt = end - j0; if (cnt > 8) cnt = 8;
        int ss[8];
        #pragma unroll
        for (int t = 0; t < 8; ++t) {
            int j = j0 + t;
            ss[t] = eidx[j < end ? j : end - 1];
        }
        u32 hh[8];
        #pragma unroll
        for (int t = 0; t < 8; ++t)
            hh[t] = HB32[(size_t)ss[t] * 64 + lane];
        #pragma unroll
        for (int t = 0; t < 8; ++t) {
            float valid = (t < cnt) ? 1.f : 0.f;
            float m0 = fmaxf(bf2f((u16)(hh[t] & 0xffff)), 0.f) + 1e-7f;
            float m1 = fmaxf(bf2f((u16)(hh[t] >> 16)),    0.f) + 1e-7f;
            float e0 = __expf(m0) * valid, e1 = __expf(m1) * valid;
            den0 += e0; num0 += m0 * e0;
            den1 += e1; num1 += m1 * e1;
        }
    }
    float a0 = num0 / (den0 + 1e-16f) + bf2f((u16)(own & 0xffff));
    float a1 = num1 / (den1 + 1e-16f) + bf2f((u16)(own >> 16));
    ((u32*)Amsg)[(size_t)n * 64 + lane] = (u32)f2bf(a0) | ((u32)f2bf(a1) << 16);
}

// ---------------- Conv GEMM: h = Amsg @ Wl + bias (+fp16 res) ----------
template<bool RES, bool OWN_MAP, bool WRITE_LN>
__global__ __launch_bounds__(256) void conv_gemm_kernel(
    const u16* __restrict__ Amsg, const int* __restrict__ own_map,
    const u16* __restrict__ Bp, int Bpbase,
    const void* __restrict__ bias, int biasoff,
    const __half* __restrict__ Resid,
    const void* __restrict__ lng, const void* __restrict__ lnb, int lnoff,
    const int* __restrict__ dt,
    __half* __restrict__ OutH, u16* __restrict__ HBout)
{
    const bool f32 = (*dt != 0);
    __shared__ u16 Bsh[16384];
    const int tid  = threadIdx.x;
    const int w    = tid >> 6;
    const int lane = tid & 63;
    const int quad = lane >> 4;
    const int cl   = lane & 15;
    const int m0   = blockIdx.x * 64;

    {
        const uint4* bsrc = (const uint4*)(Bp + Bpbase);
        uint4* bdst = (uint4*)Bsh;
        #pragma unroll
        for (int j = 0; j < 8; ++j)
            bdst[j * 256 + tid] = bsrc[j * 256 + tid];
    }

    int arow = m0 + w * 16 + cl;
    if (arow >= N_NODES) arow = N_NODES - 1;
    bf16x8 afr[4];
    #pragma unroll
    for (int kidx = 0; kidx < 4; ++kidx)
        afr[kidx] = *(const bf16x8*)(Amsg + (size_t)arow * HDIM + kidx * 32 + quad * 8);

    __syncthreads();

    f32x4 acc[8];
    #pragma unroll
    for (int ct = 0; ct < 8; ++ct) acc[ct] = (f32x4){0.f, 0.f, 0.f, 0.f};
    #pragma unroll
    for (int kidx = 0; kidx < 4; ++kidx) {
        const u16* bb = Bsh + ((size_t)(kidx * 8) * 64 + lane) * 8;
        #pragma unroll
        for (int ct = 0; ct < 8; ++ct) {
            bf16x8 b = *(const bf16x8*)(bb + (size_t)ct * 512);
            acc[ct] = __builtin_amdgcn_mfma_f32_16x16x32_bf16(afr[kidx], b, acc[ct], 0, 0, 0);
        }
    }

    #pragma unroll
    for (int reg = 0; reg < 4; ++reg) {
        int n = m0 + w * 16 + quad * 4 + reg;
        if (n >= N_NODES) continue;
        size_t rrow = 0;
        if (RES) rrow = (size_t)(OWN_MAP ? own_map[n] : n) * HDIM;
        float v[8];
        float s1 = 0.f, s2 = 0.f;
        #pragma unroll
        for (int ct = 0; ct < 8; ++ct) {
            int col = ct * 16 + cl;
            float x = acc[ct][reg] + loadF(bias, biasoff + col, f32);
            if (RES) x += __half2float(Resid[rrow + col]);
            v[ct] = x;
            OutH[(size_t)n * HDIM + col] = __float2half(x);
            s1 += x; s2 += x * x;
        }
        if (WRITE_LN) {
            #pragma unroll
            for (int o = 1; o < 16; o <<= 1) {
                s1 += __shfl_xor(s1, o, 64);
                s2 += __shfl_xor(s2, o, 64);
            }
            float mu = s1 * (1.0f / 128.0f);
            float var = s2 * (1.0f / 128.0f) - mu * mu;
            float rs = rsqrtf(fmaxf(var, 0.f) + 1e-5f);
            #pragma unroll
            for (int ct = 0; ct < 8; ++ct) {
                int col = ct * 16 + cl;
                float y = fmaxf((v[ct] - mu) * rs * loadF(lng, lnoff + col, f32)
                                + loadF(lnb, lnoff + col, f32), 0.f);
                HBout[(size_t)n * HDIM + col] = f2bf(y);
            }
        }
    }
}

// ---------------- Final: gather -> LN -> ReLU -> pred -> log_softmax ---
__global__ __launch_bounds__(64) void final_head_kernel(
    const __half* __restrict__ Hsrc, const int* __restrict__ map1,
    const int* __restrict__ fmap,
    const void* __restrict__ g, const void* __restrict__ b, int goff,
    const void* __restrict__ pw, const void* __restrict__ pb,
    const int* __restrict__ dt, void* __restrict__ out)
{
    const bool f32 = (*dt != 0);
    __shared__ float sh[HDIM];
    int i = blockIdx.x;
    int lane = threadIdx.x;
    int jj = map1[fmap[i]];
    __half2 hv = *((const __half2*)(Hsrc + (size_t)jj * HDIM) + lane);
    float2 v = __half22float2(hv);
    float mu = wave_sum(v.x + v.y) * (1.0f / 128.0f);
    float d0 = v.x - mu, d1 = v.y - mu;
    float var = wave_sum(d0 * d0 + d1 * d1) * (1.0f / 128.0f);
    float rs = rsqrtf(var + 1e-5f);
    int f0 = lane * 2;
    sh[f0]     = fmaxf(d0 * rs * loadF(g, goff + f0, f32)     + loadF(b, goff + f0, f32),     0.0f);
    sh[f0 + 1] = fmaxf(d1 * rs * loadF(g, goff + f0 + 1, f32) + loadF(b, goff + f0 + 1, f32), 0.0f);
    __syncthreads();
    float acc = -1e30f;
    if (lane < NCLS) {
        acc = loadF(pb, lane, f32);
        #pragma unroll 4
        for (int k = 0; k < HDIM; ++k)
            acc = fmaf(sh[k], loadF(pw, k * NCLS + lane, f32), acc);
    }
    float mx = wave_max(acc);
    float ex = (lane < NCLS) ? __expf(acc - mx) : 0.0f;
    float sum = wave_sum(ex);
    if (lane < NCLS) {
        float r = acc - mx - logf(sum);
        if (f32) ((float*)out)[(size_t)i * NCLS + lane] = r;
        else     ((u16*)out)[(size_t)i * NCLS + lane] = f2bf(r);
    }
}

extern "C" void kernel_launch(void* const* d_in, const int* in_sizes, int n_in,
                              void* d_out, int out_size, void* d_ws, size_t ws_size,
                              hipStream_t stream) {
    const void* x       = d_in[0];
    const int* src      = (const int*)d_in[1];
    const int* dst      = (const int*)d_in[2];
    const int* node_map = (const int*)d_in[3];
    const int* fmap     = (const int*)d_in[4];
    const void* enc_w   = d_in[5];
    const void* enc_b   = d_in[6];
    const void* gcn_w   = d_in[7];
    const void* gcn_b   = d_in[8];
    const void* ln_g    = d_in[9];
    const void* ln_b    = d_in[10];
    const void* pred_w  = d_in[11];
    const void* pred_b  = d_in[12];

    char* ws = (char*)d_ws;
    const size_t szH = (size_t)N_NODES * HDIM * sizeof(u16);     // 25.6 MB
    __half* Pa  = (__half*)ws;  ws += szH;   // h1, then h3 (fp16)
    __half* Pb  = (__half*)ws;  ws += szH;   // h2 (fp16)
    u16*   HBa  = (u16*)ws;     ws += szH;   // msg0, then msg2 (bf16)
    u16*   HBb  = (u16*)ws;     ws += szH;   // msg1 (bf16)
    u16*   Amsg = (u16*)ws;     ws += szH;   // per-layer GEMM A matrix (bf16)
    int*   FLAG = (int*)ws;     ws += 1024;
    u16*   Bp   = (u16*)ws;     ws += (size_t)(32768 + 3 * 16384) * 2 + 1024;
    int*  deg2  = (int*)ws;  ws += (size_t)2 * NP2 * 4;
    int*  rp0   = (int*)ws;  ws += (size_t)(N_NODES + 2) * 4;
    int*  rp1   = (int*)ws;  ws += (size_t)(N_NODES + 2) * 4;
    int*  ei0   = (int*)ws;  ws += (size_t)N_EDGES * 4;
    int*  ei1   = (int*)ws;  ws += (size_t)N_EDGES * 4;
    int2* tmp   = (int2*)ws; ws += (size_t)2 * N_EDGES * 8;
    int*  csum  = (int*)ws;  ws += 2048;
    int*  coff  = (int*)ws;  ws += 2048;
    int*  bcur  = (int*)ws;  ws += (size_t)2 * NCHUNK * 16 * 4 + 1024;  // padded

    dim3 blk(256);
    const int ggrid = (N_NODES + 63) / 64;       // 1563
    const int g256  = (N_NODES + 255) / 256;     // 391 (enc, 256 rows/blk)
    const int egrid = (N_EDGES + 255) / 256;
    const int agrid = (N_NODES + 3) / 4;
    const int pgrid = (32768 + 3 * 16384 + 255) / 256;

    dtype_detect_kernel<<<1, blk, 0, stream>>>((const u16*)x, FLAG);
    pack_b_kernel<<<pgrid, blk, 0, stream>>>(enc_w, gcn_w, FLAG, Bp);

    // ---- CSR build: hist -> scan -> block-radix partition -> bucket sort ----
    hipMemsetAsync(deg2, 0, (size_t)2 * NP2 * 4, stream);
    hist2_kernel<<<2 * egrid, blk, 0, stream>>>(dst, deg2, egrid);
    csum2_kernel<<<2 * NCHUNK, blk, 0, stream>>>(deg2, csum);
    coff2_kernel<<<1, blk, 0, stream>>>(csum, coff, bcur);
    scan2_kernel<<<2 * NCHUNK, blk, 0, stream>>>(deg2, coff, rp0, rp1);
    bucket_part_kernel<<<2 * PNB, blk, 0, stream>>>(src, dst, node_map, bcur, tmp);
    bucket_sort_kernel<<<2 * NCHUNK, blk, 0, stream>>>(tmp, rp0, rp1, coff, csum,
                                                       ei0, ei1);

    // encoder: HBa = bf16(x @ enc_w + enc_b)   (= msg matrix for conv0)
    enc_gemm_kernel<<<g256, blk, 0, stream>>>(x, Bp, enc_b, FLAG, HBa);

    // layer 0: Amsg = agg0(HBa)+HBa ; Pa = Amsg@w0+b0 ; HBb = relu(LN(Pa,ln0))
    agg_msg_kernel<false><<<agrid, blk, 0, stream>>>(rp0, ei0, HBa, nullptr, Amsg);
    conv_gemm_kernel<false, false, true><<<ggrid, blk, 0, stream>>>(
        Amsg, nullptr, Bp, 32768, gcn_b, 0, nullptr,
        ln_g, ln_b, 0, FLAG, Pa, HBb);

    // layer 1: Amsg = agg0(HBb)+HBb ; Pb = Amsg@w1+b1+Pa ; HBa = relu(LN(Pb,ln1))
    agg_msg_kernel<false><<<agrid, blk, 0, stream>>>(rp0, ei0, HBb, nullptr, Amsg);
    conv_gemm_kernel<true, false, true><<<ggrid, blk, 0, stream>>>(
        Amsg, nullptr, Bp, 32768 + 16384, gcn_b, 128, Pa,
        ln_g, ln_b, 128, FLAG, Pb, HBa);

    // layer 2 (permute via node_map[0], index-composed into CSR1):
    // Amsg = agg1(HBa)+HBa[map0] ; Pa = Amsg@w2+b2+Pb[map0]
    agg_msg_kernel<true><<<agrid, blk, 0, stream>>>(rp1, ei1, HBa, node_map, Amsg);
    conv_gemm_kernel<true, true, false><<<ggrid, blk, 0, stream>>>(
        Amsg, node_map, Bp, 32768 + 2 * 16384, gcn_b, 256, Pb,
        ln_g, ln_b, 256, FLAG, Pa, nullptr);

    // final head: Pa[node_map[1][final_map[i]]] -> LN(ln2) -> pred -> log_softmax
    final_head_kernel<<<NOUT_D, dim3(64), 0, stream>>>(
        Pa, node_map + N_NODES, fmap, ln_g, ln_b, 256, pred_w, pred_b, FLAG,
        (void*)d_out);
}

// Round 4
// 581.755 us; speedup vs baseline: 1.0698x; 1.0698x over previous
//
#include <hip/hip_runtime.h>
#include <hip/hip_bf16.h>
#include <hip/hip_fp16.h>

typedef unsigned short u16;
typedef unsigned int u32;

#define N_NODES 100000
#define N_EDGES 600000
#define FIN_D   256
#define HDIM    128
#define NCLS    47
#define NOUT_D  10000
#define NCHUNK  196          // ceil(N_NODES/512)
#define NP2     100352       // NCHUNK*512, padded node count
#define PCH     4096         // edges per partition block
#define PNB     ((N_EDGES + PCH - 1) / PCH)   // 147

typedef short bf16x8 __attribute__((ext_vector_type(8)));
typedef float f32x4  __attribute__((ext_vector_type(4)));

__device__ __forceinline__ float bf2f(u16 u) {
    union { u32 i; float f; } v; v.i = ((u32)u) << 16; return v.f;
}
__device__ __forceinline__ u16 f2bf(float f) {
    __hip_bfloat16 h = __float2bfloat16(f);
    return *reinterpret_cast<u16*>(&h);
}
__device__ __forceinline__ float loadF(const void* p, size_t i, bool f32) {
    if (f32) return ((const float*)p)[i];
    return bf2f(((const u16*)p)[i]);
}
__device__ __forceinline__ float wave_sum(float v) {
    #pragma unroll
    for (int o = 32; o > 0; o >>= 1) v += __shfl_xor(v, o, 64);
    return v;
}
__device__ __forceinline__ float wave_max(float v) {
    #pragma unroll
    for (int o = 32; o > 0; o >>= 1) v = fmaxf(v, __shfl_xor(v, o, 64));
    return v;
}
__device__ __forceinline__ int wave_sum_i(int v) {
    #pragma unroll
    for (int o = 32; o > 0; o >>= 1) v += __shfl_xor(v, o, 64);
    return v;
}
__device__ __forceinline__ int block_excl_scan_256(int v, int* wsum) {
    int lane = threadIdx.x & 63, wv = threadIdx.x >> 6;
    int inc = v;
    #pragma unroll
    for (int off = 1; off < 64; off <<= 1) {
        int u = __shfl_up(inc, off, 64);
        if (lane >= off) inc += u;
    }
    if (lane == 63) wsum[wv] = inc;
    __syncthreads();
    if (threadIdx.x == 0) {
        int a = 0;
        #pragma unroll
        for (int w = 0; w < 4; ++w) { int t = wsum[w]; wsum[w] = a; a += t; }
    }
    __syncthreads();
    return inc - v + wsum[wv];
}

// ---------------- dtype detector (parallel, 256 blocks) -----------------
// v5: the old 1-block version was latency-serialized at ~62us (hipcc keeps
// ~1 VGPR-dest load in flight per loop iteration). 256 blocks x 1 load each.
// Writes a COUNT into flag[1]; consumers test (flag[1] > 16).
__global__ __launch_bounds__(256) void dtype_detect_kernel(
    const u16* __restrict__ x, int* __restrict__ flag)
{
    int i = blockIdx.x * 256 + threadIdx.x;     // exactly 65536 threads
    u32 e = (x[i] >> 7) & 0xFF;
    unsigned long long b = __ballot(e >= 200);
    if ((threadIdx.x & 63) == 0) {
        int c = __popcll(b);
        if (c) atomicAdd(&flag[1], c);
    }
}

// ---------------- CSR build (both edge lists per dispatch) --------------
__global__ __launch_bounds__(256) void hist2_kernel(
    const int* __restrict__ dst, int* __restrict__ deg2, int egrid)
{
    int half = (blockIdx.x >= egrid) ? 1 : 0;
    int e = (blockIdx.x - half * egrid) * 256 + threadIdx.x;
    if (e < N_EDGES) atomicAdd(&deg2[half * NP2 + dst[half * N_EDGES + e]], 1);
}

__global__ __launch_bounds__(256) void csum2_kernel(
    const int* __restrict__ deg2, int* __restrict__ csum)
{
    __shared__ int ws[4];
    int half = (blockIdx.x >= NCHUNK) ? 1 : 0;
    int b = blockIdx.x - half * NCHUNK;
    int i0 = half * NP2 + b * 512 + threadIdx.x;
    int v = 0;
    if (b * 512 + threadIdx.x < N_NODES) v += deg2[i0];
    if (b * 512 + threadIdx.x + 256 < N_NODES) v += deg2[i0 + 256];
    v = wave_sum_i(v);
    int lane = threadIdx.x & 63, wv = threadIdx.x >> 6;
    if (lane == 0) ws[wv] = v;
    __syncthreads();
    if (threadIdx.x == 0)
        csum[blockIdx.x] = ws[0] + ws[1] + ws[2] + ws[3];
}

// exclusive-scan per-bucket counts; coff compact, bcur padded 1/cacheline.
__global__ __launch_bounds__(256) void coff2_kernel(
    const int* __restrict__ csum, int* __restrict__ coff,
    int* __restrict__ bcur)
{
    __shared__ int wsum[4];
    int t = threadIdx.x;
    for (int h = 0; h < 2; ++h) {
        int v = (t < NCHUNK) ? csum[h * NCHUNK + t] : 0;
        int excl = block_excl_scan_256(v, wsum);
        if (t < NCHUNK) {
            coff[h * NCHUNK + t] = excl;
            bcur[(h * NCHUNK + t) * 16] = excl;   // 64B-padded cursor
        }
        __syncthreads();
    }
}

__global__ __launch_bounds__(256) void scan2_kernel(
    const int* __restrict__ deg2, const int* __restrict__ coff,
    int* __restrict__ rp0, int* __restrict__ rp1)
{
    __shared__ int wsum[4];
    int half = (blockIdx.x >= NCHUNK) ? 1 : 0;
    int b = blockIdx.x - half * NCHUNK;
    const int* deg = deg2 + half * NP2;
    int* rp = half ? rp1 : rp0;
    int t = threadIdx.x;
    int i0 = b * 512 + 2 * t;
    int d0 = (i0 < N_NODES) ? deg[i0] : 0;
    int d1 = (i0 + 1 < N_NODES) ? deg[i0 + 1] : 0;
    int excl = block_excl_scan_256(d0 + d1, wsum);
    int base = coff[half * NCHUNK + b] + excl;
    if (i0 < N_NODES)     rp[i0] = base;
    if (i0 + 1 < N_NODES) rp[i0 + 1] = base + d0;
    if (b == 0 && t == 0) rp[N_NODES] = N_EDGES;
}

// Pass 1: block-local radix partition. Each block takes 4096 edges, LDS
// histogram by bucket (dst>>9), ONE global atomic per (block,bucket) onto
// a cacheline-padded cursor, then contiguous per-bucket writes to tmp.
__global__ __launch_bounds__(256) void bucket_part_kernel(
    const int* __restrict__ src, const int* __restrict__ dst,
    const int* __restrict__ comp1,
    int* __restrict__ bcur, int2* __restrict__ tmp)
{
    __shared__ int hist[NCHUNK];
    __shared__ int base[NCHUNK];
    int half = (blockIdx.x >= PNB) ? 1 : 0;
    int b = blockIdx.x - half * PNB;
    int e0 = b * PCH;
    for (int i = threadIdx.x; i < NCHUNK; i += 256) hist[i] = 0;
    __syncthreads();

    int2 loc[16];
    #pragma unroll
    for (int t = 0; t < 16; ++t) {
        int e = e0 + t * 256 + threadIdx.x;
        loc[t].y = -1;
        if (e < N_EDGES) {
            int ge = half * N_EDGES + e;
            int d = dst[ge];
            int s = src[ge];
            if (half) s = comp1[s];
            loc[t] = make_int2(s, d);
            atomicAdd(&hist[d >> 9], 1);
        }
    }
    __syncthreads();
    for (int i = threadIdx.x; i < NCHUNK; i += 256) {
        int h = hist[i];
        base[i] = (h > 0) ? atomicAdd(&bcur[(half * NCHUNK + i) * 16], h) : 0;
        hist[i] = 0;      // reuse as block-local cursor
    }
    __syncthreads();
    #pragma unroll
    for (int t = 0; t < 16; ++t) {
        if (loc[t].y >= 0) {
            int bk = loc[t].y >> 9;
            int pos = base[bk] + atomicAdd(&hist[bk], 1);
            tmp[(size_t)half * N_EDGES + pos] = loc[t];
        }
    }
}

// Pass 2: one block per bucket; LDS cursors from rp; sequential read of the
// bucket's pairs, LDS-atomic rank, write into the bucket's contiguous
// output window of ei (L2-resident, written once).
__global__ __launch_bounds__(256) void bucket_sort_kernel(
    const int2* __restrict__ tmp,
    const int* __restrict__ rp0, const int* __restrict__ rp1,
    const int* __restrict__ coff, const int* __restrict__ csum,
    int* __restrict__ ei0, int* __restrict__ ei1)
{
    __shared__ int cur[512];
    int half = (blockIdx.x >= NCHUNK) ? 1 : 0;
    int b = blockIdx.x - half * NCHUNK;
    const int* rp = half ? rp1 : rp0;
    int* ei = half ? ei1 : ei0;
    int n0 = b * 512;
    #pragma unroll
    for (int i = threadIdx.x; i < 512; i += 256) {
        int n = n0 + i;
        cur[i] = (n < N_NODES) ? rp[n] : 0;
    }
    __syncthreads();
    int beg = coff[half * NCHUNK + b];
    int end = beg + csum[half * NCHUNK + b];
    for (int i = beg + threadIdx.x; i < end; i += 256) {
        int2 p = tmp[(size_t)half * N_EDGES + i];
        int pos = atomicAdd(&cur[p.y & 511], 1);
        ei[pos] = p.x;
    }
}

// ---------------- Weight pre-pack into MFMA B-fragment order -----------
__global__ __launch_bounds__(256) void pack_b_kernel(
    const void* __restrict__ enc_w, const void* __restrict__ gcn_w,
    const int* __restrict__ dt, u16* __restrict__ Bp)
{
    const bool f32 = (dt[1] > 16);
    int o = blockIdx.x * 256 + threadIdx.x;
    if (o >= 32768 + 3 * 16384) return;
    const void* srcp; size_t soff; int m;
    if (o < 32768) { srcp = enc_w; soff = 0; m = o; }
    else {
        int l = (o - 32768) >> 14;
        srcp = gcn_w; soff = (size_t)l * 16384; m = (o - 32768) & 16383;
    }
    int j    = m & 7;
    int lane = (m >> 3) & 63;
    int ct   = (m >> 9) & 7;
    int kidx = m >> 12;
    int k = kidx * 32 + (lane >> 4) * 8 + j;
    int n = ct * 16 + (lane & 15);
    Bp[o] = f2bf(loadF(srcp, soff + (size_t)k * HDIM + n, f32));
}

// ---------------- Encoder GEMM: HB0 = bf16(x @ enc_w + enc_b) ----------
// v5: NO VGPR-dest global loads anywhere in the K-loop. A is staged per
// k-chunk through global_load_lds into a double-buffered LDS region
// (hardware-pipelined, vmcnt-counted, no register dependency -> the one
// load path hipcc cannot serialize; proven by v4's B-stage and the guide's
// m97 ladder). 512 threads, 256 rows/block, LDS = 64KB B + 2x32KB A.
#define ENC_AB(BUF) (65536 + (BUF) * 32768)

#define STAGE_A32(KC, BUF)                                                     \
    { _Pragma("unroll")                                                        \
      for (int i = 0; i < 4; ++i) {                                            \
          int rowl = i * 64 + w * 8 + (lane >> 3);                             \
          int gr = m0 + rowl; if (gr > N_NODES - 1) gr = N_NODES - 1;          \
          __builtin_amdgcn_global_load_lds(                                    \
              (const __attribute__((address_space(1))) u32*)((const char*)Araw \
                  + (size_t)gr * 1024 + (KC) * 128 + (lane & 7) * 16),         \
              (__attribute__((address_space(3))) u32*)(SH + ENC_AB(BUF)        \
                  + i * 8192 + w * 1024), 16, 0, 0);                           \
      } }

#define STAGE_A16(KC, BUF)                                                     \
    { _Pragma("unroll")                                                        \
      for (int i = 0; i < 2; ++i) {                                            \
          int rowl = i * 128 + w * 16 + (lane >> 2);                           \
          int gr = m0 + rowl; if (gr > N_NODES - 1) gr = N_NODES - 1;          \
          __builtin_amdgcn_global_load_lds(                                    \
              (const __attribute__((address_space(1))) u32*)((const char*)Araw \
                  + (size_t)gr * 512 + (KC) * 64 + (lane & 3) * 16),           \
              (__attribute__((address_space(3))) u32*)(SH + ENC_AB(BUF)        \
                  + i * 8192 + w * 1024), 16, 0, 0);                           \
      } }

__global__ __launch_bounds__(512, 1) void enc_gemm_kernel(
    const void* __restrict__ Araw, const u16* __restrict__ Bp,
    const void* __restrict__ bias, const int* __restrict__ dt,
    u16* __restrict__ OutBF)
{
    extern __shared__ char SH[];                  // 128KB dynamic
    const bool f32 = (dt[1] > 16);
    const int tid  = threadIdx.x;
    const int w    = tid >> 6;                    // 0..7
    const int lane = tid & 63;
    const int quad = lane >> 4;
    const int cl   = lane & 15;
    const int m0   = blockIdx.x * 256;

    // ---- stage B: 64KB linear via global_load_lds ----
    #pragma unroll
    for (int i = 0; i < 8; ++i) {
        int off = i * 8192 + w * 1024;
        __builtin_amdgcn_global_load_lds(
            (const __attribute__((address_space(1))) u32*)((const char*)Bp + off + lane * 16),
            (__attribute__((address_space(3))) u32*)(SH + off), 16, 0, 0);
    }
    // ---- stage A chunk 0 ----
    if (!f32) { STAGE_A16(0, 0) } else { STAGE_A32(0, 0) }

    f32x4 acc[2][8];
    #pragma unroll
    for (int t = 0; t < 2; ++t)
        #pragma unroll
        for (int ct = 0; ct < 8; ++ct) acc[t][ct] = (f32x4){0.f, 0.f, 0.f, 0.f};

    const int rl0 = w * 32 + cl;    // this lane's tile-0 local row
    __syncthreads();                // B + chunk0 staged

    #pragma unroll
    for (int k = 0; k < 8; ++k) {
        const int cur = k & 1;
        if (k < 7) {
            if (!f32) { STAGE_A16((k + 1), ((k + 1) & 1)) }
            else      { STAGE_A32((k + 1), ((k + 1) & 1)) }
        }
        bf16x8 av[2];
        if (!f32) {
            #pragma unroll
            for (int t = 0; t < 2; ++t)
                av[t] = *(const bf16x8*)(SH + ENC_AB(cur) + (rl0 + t * 16) * 64 + quad * 16);
        } else {
            #pragma unroll
            for (int t = 0; t < 2; ++t) {
                const char* p = SH + ENC_AB(cur) + (rl0 + t * 16) * 128 + quad * 32;
                float4 lo = *(const float4*)p;
                float4 hi = *(const float4*)(p + 16);
                union { u32 u[4]; bf16x8 v; } cv;
                cv.u[0] = (u32)f2bf(lo.x) | ((u32)f2bf(lo.y) << 16);
                cv.u[1] = (u32)f2bf(lo.z) | ((u32)f2bf(lo.w) << 16);
                cv.u[2] = (u32)f2bf(hi.x) | ((u32)f2bf(hi.y) << 16);
                cv.u[3] = (u32)f2bf(hi.z) | ((u32)f2bf(hi.w) << 16);
                av[t] = cv.v;
            }
        }
        #pragma unroll
        for (int ct = 0; ct < 8; ++ct) {
            bf16x8 b = *(const bf16x8*)(SH + (size_t)k * 8192 + ct * 1024 + lane * 16);
            acc[0][ct] = __builtin_amdgcn_mfma_f32_16x16x32_bf16(av[0], b, acc[0][ct], 0, 0, 0);
            acc[1][ct] = __builtin_amdgcn_mfma_f32_16x16x32_bf16(av[1], b, acc[1][ct], 0, 0, 0);
        }
        __syncthreads();            // chunk k+1 landed; all reads of cur done
    }

    #pragma unroll
    for (int t = 0; t < 2; ++t) {
        #pragma unroll
        for (int reg = 0; reg < 4; ++reg) {
            int grow = m0 + w * 32 + t * 16 + quad * 4 + reg;
            if (grow >= N_NODES) continue;
            #pragma unroll
            for (int ct = 0; ct < 8; ++ct) {
                int col = ct * 16 + cl;
                float v = acc[t][ct][reg] + loadF(bias, col, f32);
                OutBF[(size_t)grow * HDIM + col] = f2bf(v);
            }
        }
    }
}

// ---------------- Softmax aggregation -> bf16 A-matrix -----------------
template<bool OWN_MAP>
__global__ __launch_bounds__(256) void agg_msg_kernel(
    const int* __restrict__ rp, const int* __restrict__ eidx,
    const u16* __restrict__ HBin, const int* __restrict__ own_map,
    u16* __restrict__ Amsg)
{
    int wave = threadIdx.x >> 6;
    int lane = threadIdx.x & 63;
    int n = blockIdx.x * 4 + wave;
    if (n >= N_NODES) return;
    const u32* HB32 = (const u32*)HBin;
    int nn = OWN_MAP ? own_map[n] : n;
    u32 own = HB32[(size_t)nn * 64 + lane];
    int beg = rp[n], end = rp[n + 1];
    float den0 = 0.f, den1 = 0.f, num0 = 0.f, num1 = 0.f;
    for (int j0 = beg; j0 < end; j0 += 8) {
        int cnt = end - j0; if (cnt > 8) cnt = 8;
        int ss[8];
        #pragma unroll
        for (int t = 0; t < 8; ++t) {
            int j = j0 + t;
            ss[t] = eidx[j < end ? j : end - 1];
        }
        u32 hh[8];
        #pragma unroll
        for (int t = 0; t < 8; ++t)
            hh[t] = HB32[(size_t)ss[t] * 64 + lane];
        #pragma unroll
        for (int t = 0; t < 8; ++t) {
            float valid = (t < cnt) ? 1.f : 0.f;
            float m0 = fmaxf(bf2f((u16)(hh[t] & 0xffff)), 0.f) + 1e-7f;
            float m1 = fmaxf(bf2f((u16)(hh[t] >> 16)),    0.f) + 1e-7f;
            float e0 = __expf(m0) * valid, e1 = __expf(m1) * valid;
            den0 += e0; num0 += m0 * e0;
            den1 += e1; num1 += m1 * e1;
        }
    }
    float a0 = num0 / (den0 + 1e-16f) + bf2f((u16)(own & 0xffff));
    float a1 = num1 / (den1 + 1e-16f) + bf2f((u16)(own >> 16));
    ((u32*)Amsg)[(size_t)n * 64 + lane] = (u32)f2bf(a0) | ((u32)f2bf(a1) << 16);
}

// ---------------- Conv GEMM: h = Amsg @ Wl + bias (+fp16 res) ----------
template<bool RES, bool OWN_MAP, bool WRITE_LN>
__global__ __launch_bounds__(256) void conv_gemm_kernel(
    const u16* __restrict__ Amsg, const int* __restrict__ own_map,
    const u16* __restrict__ Bp, int Bpbase,
    const void* __restrict__ bias, int biasoff,
    const __half* __restrict__ Resid,
    const void* __restrict__ lng, const void* __restrict__ lnb, int lnoff,
    const int* __restrict__ dt,
    __half* __restrict__ OutH, u16* __restrict__ HBout)
{
    const bool f32 = (dt[1] > 16);
    __shared__ u16 Bsh[16384];
    const int tid  = threadIdx.x;
    const int w    = tid >> 6;
    const int lane = tid & 63;
    const int quad = lane >> 4;
    const int cl   = lane & 15;
    const int m0   = blockIdx.x * 64;

    {
        const uint4* bsrc = (const uint4*)(Bp + Bpbase);
        uint4* bdst = (uint4*)Bsh;
        #pragma unroll
        for (int j = 0; j < 8; ++j)
            bdst[j * 256 + tid] = bsrc[j * 256 + tid];
    }

    int arow = m0 + w * 16 + cl;
    if (arow >= N_NODES) arow = N_NODES - 1;
    bf16x8 afr[4];
    #pragma unroll
    for (int kidx = 0; kidx < 4; ++kidx)
        afr[kidx] = *(const bf16x8*)(Amsg + (size_t)arow * HDIM + kidx * 32 + quad * 8);

    __syncthreads();

    f32x4 acc[8];
    #pragma unroll
    for (int ct = 0; ct < 8; ++ct) acc[ct] = (f32x4){0.f, 0.f, 0.f, 0.f};
    #pragma unroll
    for (int kidx = 0; kidx < 4; ++kidx) {
        const u16* bb = Bsh + ((size_t)(kidx * 8) * 64 + lane) * 8;
        #pragma unroll
        for (int ct = 0; ct < 8; ++ct) {
            bf16x8 b = *(const bf16x8*)(bb + (size_t)ct * 512);
            acc[ct] = __builtin_amdgcn_mfma_f32_16x16x32_bf16(afr[kidx], b, acc[ct], 0, 0, 0);
        }
    }

    #pragma unroll
    for (int reg = 0; reg < 4; ++reg) {
        int n = m0 + w * 16 + quad * 4 + reg;
        if (n >= N_NODES) continue;
        size_t rrow = 0;
        if (RES) rrow = (size_t)(OWN_MAP ? own_map[n] : n) * HDIM;
        float v[8];
        float s1 = 0.f, s2 = 0.f;
        #pragma unroll
        for (int ct = 0; ct < 8; ++ct) {
            int col = ct * 16 + cl;
            float x = acc[ct][reg] + loadF(bias, biasoff + col, f32);
            if (RES) x += __half2float(Resid[rrow + col]);
            v[ct] = x;
            OutH[(size_t)n * HDIM + col] = __float2half(x);
            s1 += x; s2 += x * x;
        }
        if (WRITE_LN) {
            #pragma unroll
            for (int o = 1; o < 16; o <<= 1) {
                s1 += __shfl_xor(s1, o, 64);
                s2 += __shfl_xor(s2, o, 64);
            }
            float mu = s1 * (1.0f / 128.0f);
            float var = s2 * (1.0f / 128.0f) - mu * mu;
            float rs = rsqrtf(fmaxf(var, 0.f) + 1e-5f);
            #pragma unroll
            for (int ct = 0; ct < 8; ++ct) {
                int col = ct * 16 + cl;
                float y = fmaxf((v[ct] - mu) * rs * loadF(lng, lnoff + col, f32)
                                + loadF(lnb, lnoff + col, f32), 0.f);
                HBout[(size_t)n * HDIM + col] = f2bf(y);
            }
        }
    }
}

// ---------------- Final: gather -> LN -> ReLU -> pred -> log_softmax ---
__global__ __launch_bounds__(64) void final_head_kernel(
    const __half* __restrict__ Hsrc, const int* __restrict__ map1,
    const int* __restrict__ fmap,
    const void* __restrict__ g, const void* __restrict__ b, int goff,
    const void* __restrict__ pw, const void* __restrict__ pb,
    const int* __restrict__ dt, void* __restrict__ out)
{
    const bool f32 = (dt[1] > 16);
    __shared__ float sh[HDIM];
    int i = blockIdx.x;
    int lane = threadIdx.x;
    int jj = map1[fmap[i]];
    __half2 hv = *((const __half2*)(Hsrc + (size_t)jj * HDIM) + lane);
    float2 v = __half22float2(hv);
    float mu = wave_sum(v.x + v.y) * (1.0f / 128.0f);
    float d0 = v.x - mu, d1 = v.y - mu;
    float var = wave_sum(d0 * d0 + d1 * d1) * (1.0f / 128.0f);
    float rs = rsqrtf(var + 1e-5f);
    int f0 = lane * 2;
    sh[f0]     = fmaxf(d0 * rs * loadF(g, goff + f0, f32)     + loadF(b, goff + f0, f32),     0.0f);
    sh[f0 + 1] = fmaxf(d1 * rs * loadF(g, goff + f0 + 1, f32) + loadF(b, goff + f0 + 1, f32), 0.0f);
    __syncthreads();
    float acc = -1e30f;
    if (lane < NCLS) {
        acc = loadF(pb, lane, f32);
        #pragma unroll 4
        for (int k = 0; k < HDIM; ++k)
            acc = fmaf(sh[k], loadF(pw, k * NCLS + lane, f32), acc);
    }
    float mx = wave_max(acc);
    float ex = (lane < NCLS) ? __expf(acc - mx) : 0.0f;
    float sum = wave_sum(ex);
    if (lane < NCLS) {
        float r = acc - mx - logf(sum);
        if (f32) ((float*)out)[(size_t)i * NCLS + lane] = r;
        else     ((u16*)out)[(size_t)i * NCLS + lane] = f2bf(r);
    }
}

extern "C" void kernel_launch(void* const* d_in, const int* in_sizes, int n_in,
                              void* d_out, int out_size, void* d_ws, size_t ws_size,
                              hipStream_t stream) {
    const void* x       = d_in[0];
    const int* src      = (const int*)d_in[1];
    const int* dst      = (const int*)d_in[2];
    const int* node_map = (const int*)d_in[3];
    const int* fmap     = (const int*)d_in[4];
    const void* enc_w   = d_in[5];
    const void* enc_b   = d_in[6];
    const void* gcn_w   = d_in[7];
    const void* gcn_b   = d_in[8];
    const void* ln_g    = d_in[9];
    const void* ln_b    = d_in[10];
    const void* pred_w  = d_in[11];
    const void* pred_b  = d_in[12];

    char* ws = (char*)d_ws;
    const size_t szH = (size_t)N_NODES * HDIM * sizeof(u16);     // 25.6 MB
    __half* Pa  = (__half*)ws;  ws += szH;   // h1, then h3 (fp16)
    __half* Pb  = (__half*)ws;  ws += szH;   // h2 (fp16)
    u16*   HBa  = (u16*)ws;     ws += szH;   // msg0, then msg2 (bf16)
    u16*   HBb  = (u16*)ws;     ws += szH;   // msg1 (bf16)
    u16*   Amsg = (u16*)ws;     ws += szH;   // per-layer GEMM A matrix (bf16)
    int*   FLAG = (int*)ws;     ws += 1024;
    u16*   Bp   = (u16*)ws;     ws += (size_t)(32768 + 3 * 16384) * 2 + 1024;
    int*  deg2  = (int*)ws;  ws += (size_t)2 * NP2 * 4;
    int*  rp0   = (int*)ws;  ws += (size_t)(N_NODES + 2) * 4;
    int*  rp1   = (int*)ws;  ws += (size_t)(N_NODES + 2) * 4;
    int*  ei0   = (int*)ws;  ws += (size_t)N_EDGES * 4;
    int*  ei1   = (int*)ws;  ws += (size_t)N_EDGES * 4;
    int2* tmp   = (int2*)ws; ws += (size_t)2 * N_EDGES * 8;
    int*  csum  = (int*)ws;  ws += 2048;
    int*  coff  = (int*)ws;  ws += 2048;
    int*  bcur  = (int*)ws;  ws += (size_t)2 * NCHUNK * 16 * 4 + 1024;  // padded

    dim3 blk(256);
    const int ggrid = (N_NODES + 63) / 64;       // 1563
    const int g256  = (N_NODES + 255) / 256;     // 391 (enc, 256 rows/blk)
    const int egrid = (N_EDGES + 255) / 256;
    const int agrid = (N_NODES + 3) / 4;
    const int pgrid = (32768 + 3 * 16384 + 255) / 256;

    hipMemsetAsync(FLAG, 0, 64, stream);
    dtype_detect_kernel<<<256, blk, 0, stream>>>((const u16*)x, FLAG);
    pack_b_kernel<<<pgrid, blk, 0, stream>>>(enc_w, gcn_w, FLAG, Bp);

    // ---- CSR build: hist -> scan -> block-radix partition -> bucket sort ----
    hipMemsetAsync(deg2, 0, (size_t)2 * NP2 * 4, stream);
    hist2_kernel<<<2 * egrid, blk, 0, stream>>>(dst, deg2, egrid);
    csum2_kernel<<<2 * NCHUNK, blk, 0, stream>>>(deg2, csum);
    coff2_kernel<<<1, blk, 0, stream>>>(csum, coff, bcur);
    scan2_kernel<<<2 * NCHUNK, blk, 0, stream>>>(deg2, coff, rp0, rp1);
    bucket_part_kernel<<<2 * PNB, blk, 0, stream>>>(src, dst, node_map, bcur, tmp);
    bucket_sort_kernel<<<2 * NCHUNK, blk, 0, stream>>>(tmp, rp0, rp1, coff, csum,
                                                       ei0, ei1);

    // encoder: HBa = bf16(x @ enc_w + enc_b)   (= msg matrix for conv0)
    enc_gemm_kernel<<<g256, dim3(512), 131072, stream>>>(x, Bp, enc_b, FLAG, HBa);

    // layer 0: Amsg = agg0(HBa)+HBa ; Pa = Amsg@w0+b0 ; HBb = relu(LN(Pa,ln0))
    agg_msg_kernel<false><<<agrid, blk, 0, stream>>>(rp0, ei0, HBa, nullptr, Amsg);
    conv_gemm_kernel<false, false, true><<<ggrid, blk, 0, stream>>>(
        Amsg, nullptr, Bp, 32768, gcn_b, 0, nullptr,
        ln_g, ln_b, 0, FLAG, Pa, HBb);

    // layer 1: Amsg = agg0(HBb)+HBb ; Pb = Amsg@w1+b1+Pa ; HBa = relu(LN(Pb,ln1))
    agg_msg_kernel<false><<<agrid, blk, 0, stream>>>(rp0, ei0, HBb, nullptr, Amsg);
    conv_gemm_kernel<true, false, true><<<ggrid, blk, 0, stream>>>(
        Amsg, nullptr, Bp, 32768 + 16384, gcn_b, 128, Pa,
        ln_g, ln_b, 128, FLAG, Pb, HBa);

    // layer 2 (permute via node_map[0], index-composed into CSR1):
    // Amsg = agg1(HBa)+HBa[map0] ; Pa = Amsg@w2+b2+Pb[map0]
    agg_msg_kernel<true><<<agrid, blk, 0, stream>>>(rp1, ei1, HBa, node_map, Amsg);
    conv_gemm_kernel<true, true, false><<<ggrid, blk, 0, stream>>>(
        Amsg, node_map, Bp, 32768 + 2 * 16384, gcn_b, 256, Pb,
        ln_g, ln_b, 256, FLAG, Pa, nullptr);

    // final head: Pa[node_map[1][final_map[i]]] -> LN(ln2) -> pred -> log_softmax
    final_head_kernel<<<NOUT_D, dim3(64), 0, stream>>>(
        Pa, node_map + N_NODES, fmap, ln_g, ln_b, 256, pred_w, pred_b, FLAG,
        (void*)d_out);
}

// Round 5
// 575.321 us; speedup vs baseline: 1.0817x; 1.0112x over previous
//
#include <hip/hip_runtime.h>
#include <hip/hip_bf16.h>
#include <hip/hip_fp16.h>

typedef unsigned short u16;
typedef unsigned int u32;

#define N_NODES 100000
#define N_EDGES 600000
#define FIN_D   256
#define HDIM    128
#define NCLS    47
#define NOUT_D  10000
#define NCHUNK  196          // ceil(N_NODES/512)
#define NP2     100352       // NCHUNK*512, padded node count
#define PCH     4096         // edges per partition block
#define PNB     ((N_EDGES + PCH - 1) / PCH)   // 147

typedef short bf16x8 __attribute__((ext_vector_type(8)));
typedef float f32x4  __attribute__((ext_vector_type(4)));

#define GPTR(p) (const __attribute__((address_space(1))) u32*)(p)
#define LPTR(p) (__attribute__((address_space(3))) u32*)(p)

__device__ __forceinline__ float bf2f(u16 u) {
    union { u32 i; float f; } v; v.i = ((u32)u) << 16; return v.f;
}
__device__ __forceinline__ u16 f2bf(float f) {
    __hip_bfloat16 h = __float2bfloat16(f);
    return *reinterpret_cast<u16*>(&h);
}
__device__ __forceinline__ float loadF(const void* p, size_t i, bool f32) {
    if (f32) return ((const float*)p)[i];
    return bf2f(((const u16*)p)[i]);
}
__device__ __forceinline__ float wave_sum(float v) {
    #pragma unroll
    for (int o = 32; o > 0; o >>= 1) v += __shfl_xor(v, o, 64);
    return v;
}
__device__ __forceinline__ float wave_max(float v) {
    #pragma unroll
    for (int o = 32; o > 0; o >>= 1) v = fmaxf(v, __shfl_xor(v, o, 64));
    return v;
}
__device__ __forceinline__ int wave_sum_i(int v) {
    #pragma unroll
    for (int o = 32; o > 0; o >>= 1) v += __shfl_xor(v, o, 64);
    return v;
}
__device__ __forceinline__ int block_excl_scan_256(int v, int* wsum) {
    int lane = threadIdx.x & 63, wv = threadIdx.x >> 6;
    int inc = v;
    #pragma unroll
    for (int off = 1; off < 64; off <<= 1) {
        int u = __shfl_up(inc, off, 64);
        if (lane >= off) inc += u;
    }
    if (lane == 63) wsum[wv] = inc;
    __syncthreads();
    if (threadIdx.x == 0) {
        int a = 0;
        #pragma unroll
        for (int w = 0; w < 4; ++w) { int t = wsum[w]; wsum[w] = a; a += t; }
    }
    __syncthreads();
    return inc - v + wsum[wv];
}

// ---------------- dtype detector (parallel, 256 blocks) -----------------
__global__ __launch_bounds__(256) void dtype_detect_kernel(
    const u16* __restrict__ x, int* __restrict__ flag)
{
    int i = blockIdx.x * 256 + threadIdx.x;     // exactly 65536 threads
    u32 e = (x[i] >> 7) & 0xFF;
    unsigned long long b = __ballot(e >= 200);
    if ((threadIdx.x & 63) == 0) {
        int c = __popcll(b);
        if (c) atomicAdd(&flag[1], c);
    }
}

// ---------------- CSR build (both edge lists per dispatch) --------------
__global__ __launch_bounds__(256) void hist2_kernel(
    const int* __restrict__ dst, int* __restrict__ deg2, int egrid)
{
    int half = (blockIdx.x >= egrid) ? 1 : 0;
    int e = (blockIdx.x - half * egrid) * 256 + threadIdx.x;
    if (e < N_EDGES) atomicAdd(&deg2[half * NP2 + dst[half * N_EDGES + e]], 1);
}

__global__ __launch_bounds__(256) void csum2_kernel(
    const int* __restrict__ deg2, int* __restrict__ csum)
{
    __shared__ int ws[4];
    int half = (blockIdx.x >= NCHUNK) ? 1 : 0;
    int b = blockIdx.x - half * NCHUNK;
    int i0 = half * NP2 + b * 512 + threadIdx.x;
    int v = 0;
    if (b * 512 + threadIdx.x < N_NODES) v += deg2[i0];
    if (b * 512 + threadIdx.x + 256 < N_NODES) v += deg2[i0 + 256];
    v = wave_sum_i(v);
    int lane = threadIdx.x & 63, wv = threadIdx.x >> 6;
    if (lane == 0) ws[wv] = v;
    __syncthreads();
    if (threadIdx.x == 0)
        csum[blockIdx.x] = ws[0] + ws[1] + ws[2] + ws[3];
}

// exclusive-scan per-bucket counts; coff compact, bcur padded 1/cacheline.
__global__ __launch_bounds__(256) void coff2_kernel(
    const int* __restrict__ csum, int* __restrict__ coff,
    int* __restrict__ bcur)
{
    __shared__ int wsum[4];
    int t = threadIdx.x;
    for (int h = 0; h < 2; ++h) {
        int v = (t < NCHUNK) ? csum[h * NCHUNK + t] : 0;
        int excl = block_excl_scan_256(v, wsum);
        if (t < NCHUNK) {
            coff[h * NCHUNK + t] = excl;
            bcur[(h * NCHUNK + t) * 16] = excl;   // 64B-padded cursor
        }
        __syncthreads();
    }
}

__global__ __launch_bounds__(256) void scan2_kernel(
    const int* __restrict__ deg2, const int* __restrict__ coff,
    int* __restrict__ rp0, int* __restrict__ rp1)
{
    __shared__ int wsum[4];
    int half = (blockIdx.x >= NCHUNK) ? 1 : 0;
    int b = blockIdx.x - half * NCHUNK;
    const int* deg = deg2 + half * NP2;
    int* rp = half ? rp1 : rp0;
    int t = threadIdx.x;
    int i0 = b * 512 + 2 * t;
    int d0 = (i0 < N_NODES) ? deg[i0] : 0;
    int d1 = (i0 + 1 < N_NODES) ? deg[i0 + 1] : 0;
    int excl = block_excl_scan_256(d0 + d1, wsum);
    int base = coff[half * NCHUNK + b] + excl;
    if (i0 < N_NODES)     rp[i0] = base;
    if (i0 + 1 < N_NODES) rp[i0 + 1] = base + d0;
    if (b == 0 && t == 0) rp[N_NODES] = N_EDGES;
}

// Pass 1: block-local radix partition.
__global__ __launch_bounds__(256) void bucket_part_kernel(
    const int* __restrict__ src, const int* __restrict__ dst,
    const int* __restrict__ comp1,
    int* __restrict__ bcur, int2* __restrict__ tmp)
{
    __shared__ int hist[NCHUNK];
    __shared__ int base[NCHUNK];
    int half = (blockIdx.x >= PNB) ? 1 : 0;
    int b = blockIdx.x - half * PNB;
    int e0 = b * PCH;
    for (int i = threadIdx.x; i < NCHUNK; i += 256) hist[i] = 0;
    __syncthreads();

    int2 loc[16];
    #pragma unroll
    for (int t = 0; t < 16; ++t) {
        int e = e0 + t * 256 + threadIdx.x;
        loc[t].y = -1;
        if (e < N_EDGES) {
            int ge = half * N_EDGES + e;
            int d = dst[ge];
            int s = src[ge];
            if (half) s = comp1[s];
            loc[t] = make_int2(s, d);
            atomicAdd(&hist[d >> 9], 1);
        }
    }
    __syncthreads();
    for (int i = threadIdx.x; i < NCHUNK; i += 256) {
        int h = hist[i];
        base[i] = (h > 0) ? atomicAdd(&bcur[(half * NCHUNK + i) * 16], h) : 0;
        hist[i] = 0;      // reuse as block-local cursor
    }
    __syncthreads();
    #pragma unroll
    for (int t = 0; t < 16; ++t) {
        if (loc[t].y >= 0) {
            int bk = loc[t].y >> 9;
            int pos = base[bk] + atomicAdd(&hist[bk], 1);
            tmp[(size_t)half * N_EDGES + pos] = loc[t];
        }
    }
}

// Pass 2: one block per bucket.
__global__ __launch_bounds__(256) void bucket_sort_kernel(
    const int2* __restrict__ tmp,
    const int* __restrict__ rp0, const int* __restrict__ rp1,
    const int* __restrict__ coff, const int* __restrict__ csum,
    int* __restrict__ ei0, int* __restrict__ ei1)
{
    __shared__ int cur[512];
    int half = (blockIdx.x >= NCHUNK) ? 1 : 0;
    int b = blockIdx.x - half * NCHUNK;
    const int* rp = half ? rp1 : rp0;
    int* ei = half ? ei1 : ei0;
    int n0 = b * 512;
    #pragma unroll
    for (int i = threadIdx.x; i < 512; i += 256) {
        int n = n0 + i;
        cur[i] = (n < N_NODES) ? rp[n] : 0;
    }
    __syncthreads();
    int beg = coff[half * NCHUNK + b];
    int end = beg + csum[half * NCHUNK + b];
    for (int i = beg + threadIdx.x; i < end; i += 256) {
        int2 p = tmp[(size_t)half * N_EDGES + i];
        int pos = atomicAdd(&cur[p.y & 511], 1);
        ei[pos] = p.x;
    }
}

// ---------------- Weight pre-pack into MFMA B-fragment order -----------
__global__ __launch_bounds__(256) void pack_b_kernel(
    const void* __restrict__ enc_w, const void* __restrict__ gcn_w,
    const int* __restrict__ dt, u16* __restrict__ Bp)
{
    const bool f32 = (dt[1] > 16);
    int o = blockIdx.x * 256 + threadIdx.x;
    if (o >= 32768 + 3 * 16384) return;
    const void* srcp; size_t soff; int m;
    if (o < 32768) { srcp = enc_w; soff = 0; m = o; }
    else {
        int l = (o - 32768) >> 14;
        srcp = gcn_w; soff = (size_t)l * 16384; m = (o - 32768) & 16383;
    }
    int j    = m & 7;
    int lane = (m >> 3) & 63;
    int ct   = (m >> 9) & 7;
    int kidx = m >> 12;
    int k = kidx * 32 + (lane >> 4) * 8 + j;
    int n = ct * 16 + (lane & 15);
    Bp[o] = f2bf(loadF(srcp, soff + (size_t)k * HDIM + n, f32));
}

// ---------------- Encoder GEMM: HB0 = bf16(x @ enc_w + enc_b) ----------
// v6: 16-row blocks, LDS = exactly 80KB (64KB B + 16KB A) -> 2 blocks/CU
// so one block's stage streams while the other computes. EVERY VMEM
// instruction is a contiguous 1KB segment (full x-row or 1KB of B) via
// global_load_lds; A's LDS layout is XOR-swizzled by permuting the SOURCE
// lane addresses (dest must stay linear). One barrier per block; the MFMA
// loop is pure LDS, b128-conflict-optimal on both A and B reads.
__global__ __launch_bounds__(256, 2) void enc_gemm_kernel(
    const void* __restrict__ Araw, const u16* __restrict__ Bp,
    const void* __restrict__ bias, const int* __restrict__ dt,
    u16* __restrict__ OutBF)
{
    extern __shared__ char SH[];                  // 80KB: [0,64K)=B, [64K,80K)=A
    const bool f32 = (dt[1] > 16);
    const int tid  = threadIdx.x;
    const int w    = tid >> 6;                    // 0..3
    const int lane = tid & 63;
    const int quad = lane >> 4;
    const int cl   = lane & 15;
    const int m0   = blockIdx.x * 16;

    // ---- stage B: 64 x 1KB contiguous, 16 instrs/wave ----
    #pragma unroll
    for (int i = 0; i < 16; ++i) {
        int off = (w * 16 + i) * 1024;
        __builtin_amdgcn_global_load_lds(
            GPTR((const char*)Bp + off + lane * 16),
            LPTR(SH + off), 16, 0, 0);
    }
    // ---- stage A: full rows, source-swizzled, linear LDS dest ----
    if (f32) {
        #pragma unroll
        for (int i = 0; i < 4; ++i) {
            int row = w * 4 + i;                          // uniform per instr
            int src = (lane * 16) ^ ((row & 7) << 4);     // permuted within 1KB row
            __builtin_amdgcn_global_load_lds(
                GPTR((const char*)Araw + (size_t)(m0 + row) * 1024 + src),
                LPTR(SH + 65536 + row * 1024), 16, 0, 0);
        }
    } else {
        #pragma unroll
        for (int i = 0; i < 2; ++i) {
            int r0 = (w * 2 + i) * 2;                     // 2 rows per instr
            int row = r0 + (lane >> 5);
            int src = ((lane & 31) * 16) ^ ((row & 7) << 4);
            __builtin_amdgcn_global_load_lds(
                GPTR((const char*)Araw + (size_t)(m0 + row) * 512 + src),
                LPTR(SH + 65536 + r0 * 512), 16, 0, 0);
        }
    }

    f32x4 acc[2];
    acc[0] = (f32x4){0.f, 0.f, 0.f, 0.f};
    acc[1] = (f32x4){0.f, 0.f, 0.f, 0.f};
    const int ct0 = w * 2;
    const int swz = (cl & 7) << 4;

    __syncthreads();            // drains all global_load_lds (vmcnt 0)

    #pragma unroll
    for (int k = 0; k < 8; ++k) {
        bf16x8 av;
        if (f32) {
            const char* rb = SH + 65536 + cl * 1024;
            int lo = (k * 128 + quad * 32) ^ swz;
            float4 v0 = *(const float4*)(rb + lo);
            float4 v1 = *(const float4*)(rb + (lo ^ 16));
            union { u32 u[4]; bf16x8 v; } cv;
            cv.u[0] = (u32)f2bf(v0.x) | ((u32)f2bf(v0.y) << 16);
            cv.u[1] = (u32)f2bf(v0.z) | ((u32)f2bf(v0.w) << 16);
            cv.u[2] = (u32)f2bf(v1.x) | ((u32)f2bf(v1.y) << 16);
            cv.u[3] = (u32)f2bf(v1.z) | ((u32)f2bf(v1.w) << 16);
            av = cv.v;
        } else {
            const char* rb = SH + 65536 + cl * 512;
            av = *(const bf16x8*)(rb + ((k * 64 + quad * 16) ^ swz));
        }
        #pragma unroll
        for (int c = 0; c < 2; ++c) {
            bf16x8 b = *(const bf16x8*)(SH + k * 8192 + (ct0 + c) * 1024 + lane * 16);
            acc[c] = __builtin_amdgcn_mfma_f32_16x16x32_bf16(av, b, acc[c], 0, 0, 0);
        }
    }

    #pragma unroll
    for (int reg = 0; reg < 4; ++reg) {
        int grow = m0 + quad * 4 + reg;
        #pragma unroll
        for (int c = 0; c < 2; ++c) {
            int col = (ct0 + c) * 16 + cl;
            float v = acc[c][reg] + loadF(bias, col, f32);
            OutBF[(size_t)grow * HDIM + col] = f2bf(v);
        }
    }
}

// ---------------- Softmax aggregation -> bf16 A-matrix -----------------
template<bool OWN_MAP>
__global__ __launch_bounds__(256) void agg_msg_kernel(
    const int* __restrict__ rp, const int* __restrict__ eidx,
    const u16* __restrict__ HBin, const int* __restrict__ own_map,
    u16* __restrict__ Amsg)
{
    int wave = threadIdx.x >> 6;
    int lane = threadIdx.x & 63;
    int n = blockIdx.x * 4 + wave;
    if (n >= N_NODES) return;
    const u32* HB32 = (const u32*)HBin;
    int nn = OWN_MAP ? own_map[n] : n;
    u32 own = HB32[(size_t)nn * 64 + lane];
    int beg = rp[n], end = rp[n + 1];
    float den0 = 0.f, den1 = 0.f, num0 = 0.f, num1 = 0.f;
    for (int j0 = beg; j0 < end; j0 += 8) {
        int cnt = end - j0; if (cnt > 8) cnt = 8;
        int ss[8];
        #pragma unroll
        for (int t = 0; t < 8; ++t) {
            int j = j0 + t;
            ss[t] = eidx[j < end ? j : end - 1];
        }
        u32 hh[8];
        #pragma unroll
        for (int t = 0; t < 8; ++t)
            hh[t] = HB32[(size_t)ss[t] * 64 + lane];
        #pragma unroll
        for (int t = 0; t < 8; ++t) {
            float valid = (t < cnt) ? 1.f : 0.f;
            float m0 = fmaxf(bf2f((u16)(hh[t] & 0xffff)), 0.f) + 1e-7f;
            float m1 = fmaxf(bf2f((u16)(hh[t] >> 16)),    0.f) + 1e-7f;
            float e0 = __expf(m0) * valid, e1 = __expf(m1) * valid;
            den0 += e0; num0 += m0 * e0;
            den1 += e1; num1 += m1 * e1;
        }
    }
    float a0 = num0 / (den0 + 1e-16f) + bf2f((u16)(own & 0xffff));
    float a1 = num1 / (den1 + 1e-16f) + bf2f((u16)(own >> 16));
    ((u32*)Amsg)[(size_t)n * 64 + lane] = (u32)f2bf(a0) | ((u32)f2bf(a1) << 16);
}

// ---------------- Conv GEMM: h = Amsg @ Wl + bias (+fp16 res) ----------
template<bool RES, bool OWN_MAP, bool WRITE_LN>
__global__ __launch_bounds__(256) void conv_gemm_kernel(
    const u16* __restrict__ Amsg, const int* __restrict__ own_map,
    const u16* __restrict__ Bp, int Bpbase,
    const void* __restrict__ bias, int biasoff,
    const __half* __restrict__ Resid,
    const void* __restrict__ lng, const void* __restrict__ lnb, int lnoff,
    const int* __restrict__ dt,
    __half* __restrict__ OutH, u16* __restrict__ HBout)
{
    const bool f32 = (dt[1] > 16);
    __shared__ u16 Bsh[16384];
    const int tid  = threadIdx.x;
    const int w    = tid >> 6;
    const int lane = tid & 63;
    const int quad = lane >> 4;
    const int cl   = lane & 15;
    const int m0   = blockIdx.x * 64;

    {
        const uint4* bsrc = (const uint4*)(Bp + Bpbase);
        uint4* bdst = (uint4*)Bsh;
        #pragma unroll
        for (int j = 0; j < 8; ++j)
            bdst[j * 256 + tid] = bsrc[j * 256 + tid];
    }

    int arow = m0 + w * 16 + cl;
    if (arow >= N_NODES) arow = N_NODES - 1;
    bf16x8 afr[4];
    #pragma unroll
    for (int kidx = 0; kidx < 4; ++kidx)
        afr[kidx] = *(const bf16x8*)(Amsg + (size_t)arow * HDIM + kidx * 32 + quad * 8);

    __syncthreads();

    f32x4 acc[8];
    #pragma unroll
    for (int ct = 0; ct < 8; ++ct) acc[ct] = (f32x4){0.f, 0.f, 0.f, 0.f};
    #pragma unroll
    for (int kidx = 0; kidx < 4; ++kidx) {
        const u16* bb = Bsh + ((size_t)(kidx * 8) * 64 + lane) * 8;
        #pragma unroll
        for (int ct = 0; ct < 8; ++ct) {
            bf16x8 b = *(const bf16x8*)(bb + (size_t)ct * 512);
            acc[ct] = __builtin_amdgcn_mfma_f32_16x16x32_bf16(afr[kidx], b, acc[ct], 0, 0, 0);
        }
    }

    #pragma unroll
    for (int reg = 0; reg < 4; ++reg) {
        int n = m0 + w * 16 + quad * 4 + reg;
        if (n >= N_NODES) continue;
        size_t rrow = 0;
        if (RES) rrow = (size_t)(OWN_MAP ? own_map[n] : n) * HDIM;
        float v[8];
        float s1 = 0.f, s2 = 0.f;
        #pragma unroll
        for (int ct = 0; ct < 8; ++ct) {
            int col = ct * 16 + cl;
            float x = acc[ct][reg] + loadF(bias, biasoff + col, f32);
            if (RES) x += __half2float(Resid[rrow + col]);
            v[ct] = x;
            OutH[(size_t)n * HDIM + col] = __float2half(x);
            s1 += x; s2 += x * x;
        }
        if (WRITE_LN) {
            #pragma unroll
            for (int o = 1; o < 16; o <<= 1) {
                s1 += __shfl_xor(s1, o, 64);
                s2 += __shfl_xor(s2, o, 64);
            }
            float mu = s1 * (1.0f / 128.0f);
            float var = s2 * (1.0f / 128.0f) - mu * mu;
            float rs = rsqrtf(fmaxf(var, 0.f) + 1e-5f);
            #pragma unroll
            for (int ct = 0; ct < 8; ++ct) {
                int col = ct * 16 + cl;
                float y = fmaxf((v[ct] - mu) * rs * loadF(lng, lnoff + col, f32)
                                + loadF(lnb, lnoff + col, f32), 0.f);
                HBout[(size_t)n * HDIM + col] = f2bf(y);
            }
        }
    }
}

// ---------------- Final: gather -> LN -> ReLU -> pred -> log_softmax ---
__global__ __launch_bounds__(64) void final_head_kernel(
    const __half* __restrict__ Hsrc, const int* __restrict__ map1,
    const int* __restrict__ fmap,
    const void* __restrict__ g, const void* __restrict__ b, int goff,
    const void* __restrict__ pw, const void* __restrict__ pb,
    const int* __restrict__ dt, void* __restrict__ out)
{
    const bool f32 = (dt[1] > 16);
    __shared__ float sh[HDIM];
    int i = blockIdx.x;
    int lane = threadIdx.x;
    int jj = map1[fmap[i]];
    __half2 hv = *((const __half2*)(Hsrc + (size_t)jj * HDIM) + lane);
    float2 v = __half22float2(hv);
    float mu = wave_sum(v.x + v.y) * (1.0f / 128.0f);
    float d0 = v.x - mu, d1 = v.y - mu;
    float var = wave_sum(d0 * d0 + d1 * d1) * (1.0f / 128.0f);
    float rs = rsqrtf(var + 1e-5f);
    int f0 = lane * 2;
    sh[f0]     = fmaxf(d0 * rs * loadF(g, goff + f0, f32)     + loadF(b, goff + f0, f32),     0.0f);
    sh[f0 + 1] = fmaxf(d1 * rs * loadF(g, goff + f0 + 1, f32) + loadF(b, goff + f0 + 1, f32), 0.0f);
    __syncthreads();
    float acc = -1e30f;
    if (lane < NCLS) {
        acc = loadF(pb, lane, f32);
        #pragma unroll 4
        for (int k = 0; k < HDIM; ++k)
            acc = fmaf(sh[k], loadF(pw, k * NCLS + lane, f32), acc);
    }
    float mx = wave_max(acc);
    float ex = (lane < NCLS) ? __expf(acc - mx) : 0.0f;
    float sum = wave_sum(ex);
    if (lane < NCLS) {
        float r = acc - mx - logf(sum);
        if (f32) ((float*)out)[(size_t)i * NCLS + lane] = r;
        else     ((u16*)out)[(size_t)i * NCLS + lane] = f2bf(r);
    }
}

extern "C" void kernel_launch(void* const* d_in, const int* in_sizes, int n_in,
                              void* d_out, int out_size, void* d_ws, size_t ws_size,
                              hipStream_t stream) {
    const void* x       = d_in[0];
    const int* src      = (const int*)d_in[1];
    const int* dst      = (const int*)d_in[2];
    const int* node_map = (const int*)d_in[3];
    const int* fmap     = (const int*)d_in[4];
    const void* enc_w   = d_in[5];
    const void* enc_b   = d_in[6];
    const void* gcn_w   = d_in[7];
    const void* gcn_b   = d_in[8];
    const void* ln_g    = d_in[9];
    const void* ln_b    = d_in[10];
    const void* pred_w  = d_in[11];
    const void* pred_b  = d_in[12];

    char* ws = (char*)d_ws;
    const size_t szH = (size_t)N_NODES * HDIM * sizeof(u16);     // 25.6 MB
    __half* Pa  = (__half*)ws;  ws += szH;   // h1, then h3 (fp16)
    __half* Pb  = (__half*)ws;  ws += szH;   // h2 (fp16)
    u16*   HBa  = (u16*)ws;     ws += szH;   // msg0, then msg2 (bf16)
    u16*   HBb  = (u16*)ws;     ws += szH;   // msg1 (bf16)
    u16*   Amsg = (u16*)ws;     ws += szH;   // per-layer GEMM A matrix (bf16)
    int*   FLAG = (int*)ws;     ws += 1024;
    u16*   Bp   = (u16*)ws;     ws += (size_t)(32768 + 3 * 16384) * 2 + 1024;
    int*  deg2  = (int*)ws;  ws += (size_t)2 * NP2 * 4;
    int*  rp0   = (int*)ws;  ws += (size_t)(N_NODES + 2) * 4;
    int*  rp1   = (int*)ws;  ws += (size_t)(N_NODES + 2) * 4;
    int*  ei0   = (int*)ws;  ws += (size_t)N_EDGES * 4;
    int*  ei1   = (int*)ws;  ws += (size_t)N_EDGES * 4;
    int2* tmp   = (int2*)ws; ws += (size_t)2 * N_EDGES * 8;
    int*  csum  = (int*)ws;  ws += 2048;
    int*  coff  = (int*)ws;  ws += 2048;
    int*  bcur  = (int*)ws;  ws += (size_t)2 * NCHUNK * 16 * 4 + 1024;  // padded

    dim3 blk(256);
    const int ggrid = (N_NODES + 63) / 64;       // 1563
    const int g16   = (N_NODES + 15) / 16;       // 6250 (enc, 16 rows/blk)
    const int egrid = (N_EDGES + 255) / 256;
    const int agrid = (N_NODES + 3) / 4;
    const int pgrid = (32768 + 3 * 16384 + 255) / 256;

    hipMemsetAsync(FLAG, 0, 64, stream);
    dtype_detect_kernel<<<256, blk, 0, stream>>>((const u16*)x, FLAG);
    pack_b_kernel<<<pgrid, blk, 0, stream>>>(enc_w, gcn_w, FLAG, Bp);

    // ---- CSR build: hist -> scan -> block-radix partition -> bucket sort ----
    hipMemsetAsync(deg2, 0, (size_t)2 * NP2 * 4, stream);
    hist2_kernel<<<2 * egrid, blk, 0, stream>>>(dst, deg2, egrid);
    csum2_kernel<<<2 * NCHUNK, blk, 0, stream>>>(deg2, csum);
    coff2_kernel<<<1, blk, 0, stream>>>(csum, coff, bcur);
    scan2_kernel<<<2 * NCHUNK, blk, 0, stream>>>(deg2, coff, rp0, rp1);
    bucket_part_kernel<<<2 * PNB, blk, 0, stream>>>(src, dst, node_map, bcur, tmp);
    bucket_sort_kernel<<<2 * NCHUNK, blk, 0, stream>>>(tmp, rp0, rp1, coff, csum,
                                                       ei0, ei1);

    // encoder: HBa = bf16(x @ enc_w + enc_b)   (= msg matrix for conv0)
    enc_gemm_kernel<<<g16, blk, 81920, stream>>>(x, Bp, enc_b, FLAG, HBa);

    // layer 0: Amsg = agg0(HBa)+HBa ; Pa = Amsg@w0+b0 ; HBb = relu(LN(Pa,ln0))
    agg_msg_kernel<false><<<agrid, blk, 0, stream>>>(rp0, ei0, HBa, nullptr, Amsg);
    conv_gemm_kernel<false, false, true><<<ggrid, blk, 0, stream>>>(
        Amsg, nullptr, Bp, 32768, gcn_b, 0, nullptr,
        ln_g, ln_b, 0, FLAG, Pa, HBb);

    // layer 1: Amsg = agg0(HBb)+HBb ; Pb = Amsg@w1+b1+Pa ; HBa = relu(LN(Pb,ln1))
    agg_msg_kernel<false><<<agrid, blk, 0, stream>>>(rp0, ei0, HBb, nullptr, Amsg);
    conv_gemm_kernel<true, false, true><<<ggrid, blk, 0, stream>>>(
        Amsg, nullptr, Bp, 32768 + 16384, gcn_b, 128, Pa,
        ln_g, ln_b, 128, FLAG, Pb, HBa);

    // layer 2 (permute via node_map[0], index-composed into CSR1):
    // Amsg = agg1(HBa)+HBa[map0] ; Pa = Amsg@w2+b2+Pb[map0]
    agg_msg_kernel<true><<<agrid, blk, 0, stream>>>(rp1, ei1, HBa, node_map, Amsg);
    conv_gemm_kernel<true, true, false><<<ggrid, blk, 0, stream>>>(
        Amsg, node_map, Bp, 32768 + 2 * 16384, gcn_b, 256, Pb,
        ln_g, ln_b, 256, FLAG, Pa, nullptr);

    // final head: Pa[node_map[1][final_map[i]]] -> LN(ln2) -> pred -> log_softmax
    final_head_kernel<<<NOUT_D, dim3(64), 0, stream>>>(
        Pa, node_map + N_NODES, fmap, ln_g, ln_b, 256, pred_w, pred_b, FLAG,
        (void*)d_out);
}

// Round 6
// 571.173 us; speedup vs baseline: 1.0896x; 1.0073x over previous
//
#include <hip/hip_runtime.h>
#include <hip/hip_bf16.h>
#include <hip/hip_fp16.h>

typedef unsigned short u16;
typedef unsigned int u32;

#define N_NODES 100000
#define N_EDGES 600000
#define FIN_D   256
#define HDIM    128
#define NCLS    47
#define NOUT_D  10000
#define NCHUNK  196          // ceil(N_NODES/512)
#define NP2     100352       // NCHUNK*512, padded node count
#define PCH     2048         // edges per partition block (v7: was 4096; 2x blocks)
#define PNB     ((N_EDGES + PCH - 1) / PCH)   // 293

typedef short bf16x8 __attribute__((ext_vector_type(8)));
typedef float f32x4  __attribute__((ext_vector_type(4)));

#define GPTR(p) (const __attribute__((address_space(1))) u32*)(p)
#define LPTR(p) (__attribute__((address_space(3))) u32*)(p)

__device__ __forceinline__ float bf2f(u16 u) {
    union { u32 i; float f; } v; v.i = ((u32)u) << 16; return v.f;
}
__device__ __forceinline__ u16 f2bf(float f) {
    __hip_bfloat16 h = __float2bfloat16(f);
    return *reinterpret_cast<u16*>(&h);
}
__device__ __forceinline__ float loadF(const void* p, size_t i, bool f32) {
    if (f32) return ((const float*)p)[i];
    return bf2f(((const u16*)p)[i]);
}
__device__ __forceinline__ float wave_sum(float v) {
    #pragma unroll
    for (int o = 32; o > 0; o >>= 1) v += __shfl_xor(v, o, 64);
    return v;
}
__device__ __forceinline__ float wave_max(float v) {
    #pragma unroll
    for (int o = 32; o > 0; o >>= 1) v = fmaxf(v, __shfl_xor(v, o, 64));
    return v;
}
__device__ __forceinline__ int wave_sum_i(int v) {
    #pragma unroll
    for (int o = 32; o > 0; o >>= 1) v += __shfl_xor(v, o, 64);
    return v;
}
__device__ __forceinline__ int block_excl_scan_256(int v, int* wsum) {
    int lane = threadIdx.x & 63, wv = threadIdx.x >> 6;
    int inc = v;
    #pragma unroll
    for (int off = 1; off < 64; off <<= 1) {
        int u = __shfl_up(inc, off, 64);
        if (lane >= off) inc += u;
    }
    if (lane == 63) wsum[wv] = inc;
    __syncthreads();
    if (threadIdx.x == 0) {
        int a = 0;
        #pragma unroll
        for (int w = 0; w < 4; ++w) { int t = wsum[w]; wsum[w] = a; a += t; }
    }
    __syncthreads();
    return inc - v + wsum[wv];
}

// ---------------- dtype detector (parallel, 256 blocks) -----------------
__global__ __launch_bounds__(256) void dtype_detect_kernel(
    const u16* __restrict__ x, int* __restrict__ flag)
{
    int i = blockIdx.x * 256 + threadIdx.x;     // exactly 65536 threads
    u32 e = (x[i] >> 7) & 0xFF;
    unsigned long long b = __ballot(e >= 200);
    if ((threadIdx.x & 63) == 0) {
        int c = __popcll(b);
        if (c) atomicAdd(&flag[1], c);
    }
}

// ---------------- CSR build (both edge lists per dispatch) --------------
__global__ __launch_bounds__(256) void hist2_kernel(
    const int* __restrict__ dst, int* __restrict__ deg2, int egrid)
{
    int half = (blockIdx.x >= egrid) ? 1 : 0;
    int e = (blockIdx.x - half * egrid) * 256 + threadIdx.x;
    if (e < N_EDGES) atomicAdd(&deg2[half * NP2 + dst[half * N_EDGES + e]], 1);
}

__global__ __launch_bounds__(256) void csum2_kernel(
    const int* __restrict__ deg2, int* __restrict__ csum)
{
    __shared__ int ws[4];
    int half = (blockIdx.x >= NCHUNK) ? 1 : 0;
    int b = blockIdx.x - half * NCHUNK;
    int i0 = half * NP2 + b * 512 + threadIdx.x;
    int v = 0;
    if (b * 512 + threadIdx.x < N_NODES) v += deg2[i0];
    if (b * 512 + threadIdx.x + 256 < N_NODES) v += deg2[i0 + 256];
    v = wave_sum_i(v);
    int lane = threadIdx.x & 63, wv = threadIdx.x >> 6;
    if (lane == 0) ws[wv] = v;
    __syncthreads();
    if (threadIdx.x == 0)
        csum[blockIdx.x] = ws[0] + ws[1] + ws[2] + ws[3];
}

// exclusive-scan per-bucket counts; coff compact, bcur padded 1/cacheline.
__global__ __launch_bounds__(256) void coff2_kernel(
    const int* __restrict__ csum, int* __restrict__ coff,
    int* __restrict__ bcur)
{
    __shared__ int wsum[4];
    int t = threadIdx.x;
    for (int h = 0; h < 2; ++h) {
        int v = (t < NCHUNK) ? csum[h * NCHUNK + t] : 0;
        int excl = block_excl_scan_256(v, wsum);
        if (t < NCHUNK) {
            coff[h * NCHUNK + t] = excl;
            bcur[(h * NCHUNK + t) * 16] = excl;   // 64B-padded cursor
        }
        __syncthreads();
    }
}

__global__ __launch_bounds__(256) void scan2_kernel(
    const int* __restrict__ deg2, const int* __restrict__ coff,
    int* __restrict__ rp0, int* __restrict__ rp1)
{
    __shared__ int wsum[4];
    int half = (blockIdx.x >= NCHUNK) ? 1 : 0;
    int b = blockIdx.x - half * NCHUNK;
    const int* deg = deg2 + half * NP2;
    int* rp = half ? rp1 : rp0;
    int t = threadIdx.x;
    int i0 = b * 512 + 2 * t;
    int d0 = (i0 < N_NODES) ? deg[i0] : 0;
    int d1 = (i0 + 1 < N_NODES) ? deg[i0 + 1] : 0;
    int excl = block_excl_scan_256(d0 + d1, wsum);
    int base = coff[half * NCHUNK + b] + excl;
    if (i0 < N_NODES)     rp[i0] = base;
    if (i0 + 1 < N_NODES) rp[i0 + 1] = base + d0;
    if (b == 0 && t == 0) rp[N_NODES] = N_EDGES;
}

// Pass 1: block-local radix partition. v7: PCH 2048 (2x blocks for latency
// hiding of the serialized per-thread loads).
__global__ __launch_bounds__(256) void bucket_part_kernel(
    const int* __restrict__ src, const int* __restrict__ dst,
    const int* __restrict__ comp1,
    int* __restrict__ bcur, int2* __restrict__ tmp)
{
    __shared__ int hist[NCHUNK];
    __shared__ int base[NCHUNK];
    int half = (blockIdx.x >= PNB) ? 1 : 0;
    int b = blockIdx.x - half * PNB;
    int e0 = b * PCH;
    for (int i = threadIdx.x; i < NCHUNK; i += 256) hist[i] = 0;
    __syncthreads();

    int2 loc[8];
    #pragma unroll
    for (int t = 0; t < 8; ++t) {
        int e = e0 + t * 256 + threadIdx.x;
        loc[t].y = -1;
        if (e < N_EDGES) {
            int ge = half * N_EDGES + e;
            int d = dst[ge];
            int s = src[ge];
            if (half) s = comp1[s];
            loc[t] = make_int2(s, d);
            atomicAdd(&hist[d >> 9], 1);
        }
    }
    __syncthreads();
    for (int i = threadIdx.x; i < NCHUNK; i += 256) {
        int h = hist[i];
        base[i] = (h > 0) ? atomicAdd(&bcur[(half * NCHUNK + i) * 16], h) : 0;
        hist[i] = 0;      // reuse as block-local cursor
    }
    __syncthreads();
    #pragma unroll
    for (int t = 0; t < 8; ++t) {
        if (loc[t].y >= 0) {
            int bk = loc[t].y >> 9;
            int pos = base[bk] + atomicAdd(&hist[bk], 1);
            tmp[(size_t)half * N_EDGES + pos] = loc[t];
        }
    }
}

// Pass 2: one block per bucket.
__global__ __launch_bounds__(256) void bucket_sort_kernel(
    const int2* __restrict__ tmp,
    const int* __restrict__ rp0, const int* __restrict__ rp1,
    const int* __restrict__ coff, const int* __restrict__ csum,
    int* __restrict__ ei0, int* __restrict__ ei1)
{
    __shared__ int cur[512];
    int half = (blockIdx.x >= NCHUNK) ? 1 : 0;
    int b = blockIdx.x - half * NCHUNK;
    const int* rp = half ? rp1 : rp0;
    int* ei = half ? ei1 : ei0;
    int n0 = b * 512;
    #pragma unroll
    for (int i = threadIdx.x; i < 512; i += 256) {
        int n = n0 + i;
        cur[i] = (n < N_NODES) ? rp[n] : 0;
    }
    __syncthreads();
    int beg = coff[half * NCHUNK + b];
    int end = beg + csum[half * NCHUNK + b];
    for (int i = beg + threadIdx.x; i < end; i += 256) {
        int2 p = tmp[(size_t)half * N_EDGES + i];
        int pos = atomicAdd(&cur[p.y & 511], 1);
        ei[pos] = p.x;
    }
}

// ---------------- Weight pre-pack into MFMA B-fragment order -----------
__global__ __launch_bounds__(256) void pack_b_kernel(
    const void* __restrict__ enc_w, const void* __restrict__ gcn_w,
    const int* __restrict__ dt, u16* __restrict__ Bp)
{
    const bool f32 = (dt[1] > 16);
    int o = blockIdx.x * 256 + threadIdx.x;
    if (o >= 32768 + 3 * 16384) return;
    const void* srcp; size_t soff; int m;
    if (o < 32768) { srcp = enc_w; soff = 0; m = o; }
    else {
        int l = (o - 32768) >> 14;
        srcp = gcn_w; soff = (size_t)l * 16384; m = (o - 32768) & 16383;
    }
    int j    = m & 7;
    int lane = (m >> 3) & 63;
    int ct   = (m >> 9) & 7;
    int kidx = m >> 12;
    int k = kidx * 32 + (lane >> 4) * 8 + j;
    int n = ct * 16 + (lane & 15);
    Bp[o] = f2bf(loadF(srcp, soff + (size_t)k * HDIM + n, f32));
}

// ---------------- Encoder GEMM (v6, banked at ~62us) -------------------
__global__ __launch_bounds__(256, 2) void enc_gemm_kernel(
    const void* __restrict__ Araw, const u16* __restrict__ Bp,
    const void* __restrict__ bias, const int* __restrict__ dt,
    u16* __restrict__ OutBF)
{
    extern __shared__ char SH[];                  // 80KB: [0,64K)=B, [64K,80K)=A
    const bool f32 = (dt[1] > 16);
    const int tid  = threadIdx.x;
    const int w    = tid >> 6;                    // 0..3
    const int lane = tid & 63;
    const int quad = lane >> 4;
    const int cl   = lane & 15;
    const int m0   = blockIdx.x * 16;

    #pragma unroll
    for (int i = 0; i < 16; ++i) {
        int off = (w * 16 + i) * 1024;
        __builtin_amdgcn_global_load_lds(
            GPTR((const char*)Bp + off + lane * 16),
            LPTR(SH + off), 16, 0, 0);
    }
    if (f32) {
        #pragma unroll
        for (int i = 0; i < 4; ++i) {
            int row = w * 4 + i;
            int src = (lane * 16) ^ ((row & 7) << 4);
            __builtin_amdgcn_global_load_lds(
                GPTR((const char*)Araw + (size_t)(m0 + row) * 1024 + src),
                LPTR(SH + 65536 + row * 1024), 16, 0, 0);
        }
    } else {
        #pragma unroll
        for (int i = 0; i < 2; ++i) {
            int r0 = (w * 2 + i) * 2;
            int row = r0 + (lane >> 5);
            int src = ((lane & 31) * 16) ^ ((row & 7) << 4);
            __builtin_amdgcn_global_load_lds(
                GPTR((const char*)Araw + (size_t)(m0 + row) * 512 + src),
                LPTR(SH + 65536 + r0 * 512), 16, 0, 0);
        }
    }

    f32x4 acc[2];
    acc[0] = (f32x4){0.f, 0.f, 0.f, 0.f};
    acc[1] = (f32x4){0.f, 0.f, 0.f, 0.f};
    const int ct0 = w * 2;
    const int swz = (cl & 7) << 4;

    __syncthreads();

    #pragma unroll
    for (int k = 0; k < 8; ++k) {
        bf16x8 av;
        if (f32) {
            const char* rb = SH + 65536 + cl * 1024;
            int lo = (k * 128 + quad * 32) ^ swz;
            float4 v0 = *(const float4*)(rb + lo);
            float4 v1 = *(const float4*)(rb + (lo ^ 16));
            union { u32 u[4]; bf16x8 v; } cv;
            cv.u[0] = (u32)f2bf(v0.x) | ((u32)f2bf(v0.y) << 16);
            cv.u[1] = (u32)f2bf(v0.z) | ((u32)f2bf(v0.w) << 16);
            cv.u[2] = (u32)f2bf(v1.x) | ((u32)f2bf(v1.y) << 16);
            cv.u[3] = (u32)f2bf(v1.z) | ((u32)f2bf(v1.w) << 16);
            av = cv.v;
        } else {
            const char* rb = SH + 65536 + cl * 512;
            av = *(const bf16x8*)(rb + ((k * 64 + quad * 16) ^ swz));
        }
        #pragma unroll
        for (int c = 0; c < 2; ++c) {
            bf16x8 b = *(const bf16x8*)(SH + k * 8192 + (ct0 + c) * 1024 + lane * 16);
            acc[c] = __builtin_amdgcn_mfma_f32_16x16x32_bf16(av, b, acc[c], 0, 0, 0);
        }
    }

    #pragma unroll
    for (int reg = 0; reg < 4; ++reg) {
        int grow = m0 + quad * 4 + reg;
        #pragma unroll
        for (int c = 0; c < 2; ++c) {
            int col = (ct0 + c) * 16 + cl;
            float v = acc[c][reg] + loadF(bias, col, f32);
            OutBF[(size_t)grow * HDIM + col] = f2bf(v);
        }
    }
}

// ---------------- Softmax aggregation -> bf16 A-matrix -----------------
// v7: DMA row-gather. One global_load_lds fetches FOUR 256-B source rows
// (per-lane global src = s*256 + (lane&15)*16, wave-uniform linear LDS
// dest) -> up to 16 rows in flight per chunk, wave-local vmcnt(0), then
// conflict-free LDS row reduction. Replaces the serialized hh[8] register
// gather (hipcc keeps ~1-2 VGPR-dest loads in flight; proven R0-R3).
template<bool OWN_MAP>
__global__ __launch_bounds__(256) void agg_msg_kernel(
    const int* __restrict__ rp, const int* __restrict__ eidx,
    const u16* __restrict__ HBin, const int* __restrict__ own_map,
    u16* __restrict__ Amsg)
{
    __shared__ u32 RS[4][16][64];   // 16KB: per-wave staging of 16 rows
    int wave = threadIdx.x >> 6;
    int lane = threadIdx.x & 63;
    int n = blockIdx.x * 4 + wave;
    if (n >= N_NODES) return;       // no barriers below: wave-local only
    const u32* HB32 = (const u32*)HBin;
    int nn = OWN_MAP ? own_map[n] : n;
    u32 own = HB32[(size_t)nn * 64 + lane];
    int beg = rp[n], end = rp[n + 1];
    float den0 = 0.f, den1 = 0.f, num0 = 0.f, num1 = 0.f;
    for (int c = beg; c < end; c += 16) {
        int cnt = end - c; if (cnt > 16) cnt = 16;
        int e = c + (lane & 15); if (e > end - 1) e = end - 1;
        int ei = eidx[e];                       // lanes 0..15 hold the ids
        int nI = (cnt + 3) >> 2;
        #pragma unroll
        for (int i = 0; i < 4; ++i) {
            if (i < nI) {
                int s = __shfl(ei, i * 4 + (lane >> 4), 64);
                __builtin_amdgcn_global_load_lds(
                    GPTR((const char*)HBin + (size_t)s * 256 + (lane & 15) * 16),
                    LPTR(&RS[wave][i * 4][0]), 16, 0, 0);
            }
        }
        asm volatile("s_waitcnt vmcnt(0)" ::: "memory");
        __builtin_amdgcn_sched_barrier(0);
        #pragma unroll
        for (int t = 0; t < 16; ++t) {
            if (t >= cnt) break;                // cnt is wave-uniform
            u32 h = RS[wave][t][lane];
            float m0 = fmaxf(bf2f((u16)(h & 0xffff)), 0.f) + 1e-7f;
            float m1 = fmaxf(bf2f((u16)(h >> 16)),    0.f) + 1e-7f;
            float e0 = __expf(m0), e1 = __expf(m1);
            den0 += e0; num0 += m0 * e0;
            den1 += e1; num1 += m1 * e1;
        }
        asm volatile("s_waitcnt lgkmcnt(0)" ::: "memory");  // reads done before
        __builtin_amdgcn_sched_barrier(0);                  // next DMA overwrite
    }
    float a0 = num0 / (den0 + 1e-16f) + bf2f((u16)(own & 0xffff));
    float a1 = num1 / (den1 + 1e-16f) + bf2f((u16)(own >> 16));
    ((u32*)Amsg)[(size_t)n * 64 + lane] = (u32)f2bf(a0) | ((u32)f2bf(a1) << 16);
}

// ---------------- Conv GEMM: h = Amsg @ Wl + bias (+fp16 res) ----------
// v7: B (32KB) AND the contiguous 16KB A-tile staged via global_load_lds
// (A source-XOR-swizzled; read-side XOR -> 2-way-free LDS reads). No
// VGPR-dest global loads before the single barrier.
template<bool RES, bool OWN_MAP, bool WRITE_LN>
__global__ __launch_bounds__(256) void conv_gemm_kernel(
    const u16* __restrict__ Amsg, const int* __restrict__ own_map,
    const u16* __restrict__ Bp, int Bpbase,
    const void* __restrict__ bias, int biasoff,
    const __half* __restrict__ Resid,
    const void* __restrict__ lng, const void* __restrict__ lnb, int lnoff,
    const int* __restrict__ dt,
    __half* __restrict__ OutH, u16* __restrict__ HBout)
{
    const bool f32 = (dt[1] > 16);
    __shared__ u16 Bsh[16384];      // 32KB
    __shared__ u16 Ash[8192];       // 16KB: 64 rows x 256B (swizzled)
    const int tid  = threadIdx.x;
    const int w    = tid >> 6;
    const int lane = tid & 63;
    const int quad = lane >> 4;
    const int cl   = lane & 15;
    const int m0   = blockIdx.x * 64;

    {
        const char* Bp2 = (const char*)(Bp + Bpbase);
        #pragma unroll
        for (int i = 0; i < 8; ++i)
            __builtin_amdgcn_global_load_lds(
                GPTR(Bp2 + i * 4096 + w * 1024 + lane * 16),
                LPTR((char*)Bsh + i * 4096 + w * 1024), 16, 0, 0);
        const char* Ab = (const char*)Amsg + (size_t)m0 * 256;
        #pragma unroll
        for (int i = 0; i < 4; ++i) {
            int row_local = i * 16 + w * 4 + (lane >> 4);
            int off = ((lane & 15) * 16) ^ ((row_local & 7) << 4);
            __builtin_amdgcn_global_load_lds(
                GPTR(Ab + (size_t)row_local * 256 + off),
                LPTR((char*)Ash + i * 4096 + w * 1024), 16, 0, 0);
        }
    }

    __syncthreads();    // vmcnt(0) drain + barrier (compiler-emitted)

    const int row_local = w * 16 + cl;
    const char* ar = (const char*)Ash + row_local * 256;
    const int akey = (row_local & 7) << 4;
    bf16x8 afr[4];
    #pragma unroll
    for (int kidx = 0; kidx < 4; ++kidx)
        afr[kidx] = *(const bf16x8*)(ar + ((kidx * 64 + quad * 16) ^ akey));

    f32x4 acc[8];
    #pragma unroll
    for (int ct = 0; ct < 8; ++ct) acc[ct] = (f32x4){0.f, 0.f, 0.f, 0.f};
    #pragma unroll
    for (int kidx = 0; kidx < 4; ++kidx) {
        const u16* bb = Bsh + ((size_t)(kidx * 8) * 64 + lane) * 8;
        #pragma unroll
        for (int ct = 0; ct < 8; ++ct) {
            bf16x8 b = *(const bf16x8*)(bb + (size_t)ct * 512);
            acc[ct] = __builtin_amdgcn_mfma_f32_16x16x32_bf16(afr[kidx], b, acc[ct], 0, 0, 0);
        }
    }

    #pragma unroll
    for (int reg = 0; reg < 4; ++reg) {
        int n = m0 + w * 16 + quad * 4 + reg;
        if (n >= N_NODES) continue;
        size_t rrow = 0;
        if (RES) rrow = (size_t)(OWN_MAP ? own_map[n] : n) * HDIM;
        float v[8];
        float s1 = 0.f, s2 = 0.f;
        #pragma unroll
        for (int ct = 0; ct < 8; ++ct) {
            int col = ct * 16 + cl;
            float x = acc[ct][reg] + loadF(bias, biasoff + col, f32);
            if (RES) x += __half2float(Resid[rrow + col]);
            v[ct] = x;
            OutH[(size_t)n * HDIM + col] = __float2half(x);
            s1 += x; s2 += x * x;
        }
        if (WRITE_LN) {
            #pragma unroll
            for (int o = 1; o < 16; o <<= 1) {
                s1 += __shfl_xor(s1, o, 64);
                s2 += __shfl_xor(s2, o, 64);
            }
            float mu = s1 * (1.0f / 128.0f);
            float var = s2 * (1.0f / 128.0f) - mu * mu;
            float rs = rsqrtf(fmaxf(var, 0.f) + 1e-5f);
            #pragma unroll
            for (int ct = 0; ct < 8; ++ct) {
                int col = ct * 16 + cl;
                float y = fmaxf((v[ct] - mu) * rs * loadF(lng, lnoff + col, f32)
                                + loadF(lnb, lnoff + col, f32), 0.f);
                HBout[(size_t)n * HDIM + col] = f2bf(y);
            }
        }
    }
}

// ---------------- Final: gather -> LN -> ReLU -> pred -> log_softmax ---
__global__ __launch_bounds__(64) void final_head_kernel(
    const __half* __restrict__ Hsrc, const int* __restrict__ map1,
    const int* __restrict__ fmap,
    const void* __restrict__ g, const void* __restrict__ b, int goff,
    const void* __restrict__ pw, const void* __restrict__ pb,
    const int* __restrict__ dt, void* __restrict__ out)
{
    const bool f32 = (dt[1] > 16);
    __shared__ float sh[HDIM];
    int i = blockIdx.x;
    int lane = threadIdx.x;
    int jj = map1[fmap[i]];
    __half2 hv = *((const __half2*)(Hsrc + (size_t)jj * HDIM) + lane);
    float2 v = __half22float2(hv);
    float mu = wave_sum(v.x + v.y) * (1.0f / 128.0f);
    float d0 = v.x - mu, d1 = v.y - mu;
    float var = wave_sum(d0 * d0 + d1 * d1) * (1.0f / 128.0f);
    float rs = rsqrtf(var + 1e-5f);
    int f0 = lane * 2;
    sh[f0]     = fmaxf(d0 * rs * loadF(g, goff + f0, f32)     + loadF(b, goff + f0, f32),     0.0f);
    sh[f0 + 1] = fmaxf(d1 * rs * loadF(g, goff + f0 + 1, f32) + loadF(b, goff + f0 + 1, f32), 0.0f);
    __syncthreads();
    float acc = -1e30f;
    if (lane < NCLS) {
        acc = loadF(pb, lane, f32);
        #pragma unroll 4
        for (int k = 0; k < HDIM; ++k)
            acc = fmaf(sh[k], loadF(pw, k * NCLS + lane, f32), acc);
    }
    float mx = wave_max(acc);
    float ex = (lane < NCLS) ? __expf(acc - mx) : 0.0f;
    float sum = wave_sum(ex);
    if (lane < NCLS) {
        float r = acc - mx - logf(sum);
        if (f32) ((float*)out)[(size_t)i * NCLS + lane] = r;
        else     ((u16*)out)[(size_t)i * NCLS + lane] = f2bf(r);
    }
}

extern "C" void kernel_launch(void* const* d_in, const int* in_sizes, int n_in,
                              void* d_out, int out_size, void* d_ws, size_t ws_size,
                              hipStream_t stream) {
    const void* x       = d_in[0];
    const int* src      = (const int*)d_in[1];
    const int* dst      = (const int*)d_in[2];
    const int* node_map = (const int*)d_in[3];
    const int* fmap     = (const int*)d_in[4];
    const void* enc_w   = d_in[5];
    const void* enc_b   = d_in[6];
    const void* gcn_w   = d_in[7];
    const void* gcn_b   = d_in[8];
    const void* ln_g    = d_in[9];
    const void* ln_b    = d_in[10];
    const void* pred_w  = d_in[11];
    const void* pred_b  = d_in[12];

    char* ws = (char*)d_ws;
    const size_t szH = (size_t)N_NODES * HDIM * sizeof(u16);     // 25.6 MB
    __half* Pa  = (__half*)ws;  ws += szH;   // h1, then h3 (fp16)
    __half* Pb  = (__half*)ws;  ws += szH;   // h2 (fp16)
    u16*   HBa  = (u16*)ws;     ws += szH;   // msg0, then msg2 (bf16)
    u16*   HBb  = (u16*)ws;     ws += szH;   // msg1 (bf16)
    u16*   Amsg = (u16*)ws;     ws += szH;   // per-layer GEMM A matrix (bf16)
    int*   FLAG = (int*)ws;     ws += 1024;
    u16*   Bp   = (u16*)ws;     ws += (size_t)(32768 + 3 * 16384) * 2 + 1024;
    int*  deg2  = (int*)ws;  ws += (size_t)2 * NP2 * 4;
    int*  rp0   = (int*)ws;  ws += (size_t)(N_NODES + 2) * 4;
    int*  rp1   = (int*)ws;  ws += (size_t)(N_NODES + 2) * 4;
    int*  ei0   = (int*)ws;  ws += (size_t)N_EDGES * 4;
    int*  ei1   = (int*)ws;  ws += (size_t)N_EDGES * 4;
    int2* tmp   = (int2*)ws; ws += (size_t)2 * N_EDGES * 8;
    int*  csum  = (int*)ws;  ws += 2048;
    int*  coff  = (int*)ws;  ws += 2048;
    int*  bcur  = (int*)ws;  ws += (size_t)2 * NCHUNK * 16 * 4 + 1024;  // padded

    dim3 blk(256);
    const int ggrid = (N_NODES + 63) / 64;       // 1563
    const int g16   = (N_NODES + 15) / 16;       // 6250 (enc, 16 rows/blk)
    const int egrid = (N_EDGES + 255) / 256;
    const int agrid = (N_NODES + 3) / 4;
    const int pgrid = (32768 + 3 * 16384 + 255) / 256;

    hipMemsetAsync(FLAG, 0, 64, stream);
    dtype_detect_kernel<<<256, blk, 0, stream>>>((const u16*)x, FLAG);
    pack_b_kernel<<<pgrid, blk, 0, stream>>>(enc_w, gcn_w, FLAG, Bp);

    // ---- CSR build: hist -> scan -> block-radix partition -> bucket sort ----
    hipMemsetAsync(deg2, 0, (size_t)2 * NP2 * 4, stream);
    hist2_kernel<<<2 * egrid, blk, 0, stream>>>(dst, deg2, egrid);
    csum2_kernel<<<2 * NCHUNK, blk, 0, stream>>>(deg2, csum);
    coff2_kernel<<<1, blk, 0, stream>>>(csum, coff, bcur);
    scan2_kernel<<<2 * NCHUNK, blk, 0, stream>>>(deg2, coff, rp0, rp1);
    bucket_part_kernel<<<2 * PNB, blk, 0, stream>>>(src, dst, node_map, bcur, tmp);
    bucket_sort_kernel<<<2 * NCHUNK, blk, 0, stream>>>(tmp, rp0, rp1, coff, csum,
                                                       ei0, ei1);

    // encoder: HBa = bf16(x @ enc_w + enc_b)   (= msg matrix for conv0)
    enc_gemm_kernel<<<g16, blk, 81920, stream>>>(x, Bp, enc_b, FLAG, HBa);

    // layer 0: Amsg = agg0(HBa)+HBa ; Pa = Amsg@w0+b0 ; HBb = relu(LN(Pa,ln0))
    agg_msg_kernel<false><<<agrid, blk, 0, stream>>>(rp0, ei0, HBa, nullptr, Amsg);
    conv_gemm_kernel<false, false, true><<<ggrid, blk, 0, stream>>>(
        Amsg, nullptr, Bp, 32768, gcn_b, 0, nullptr,
        ln_g, ln_b, 0, FLAG, Pa, HBb);

    // layer 1: Amsg = agg0(HBb)+HBb ; Pb = Amsg@w1+b1+Pa ; HBa = relu(LN(Pb,ln1))
    agg_msg_kernel<false><<<agrid, blk, 0, stream>>>(rp0, ei0, HBb, nullptr, Amsg);
    conv_gemm_kernel<true, false, true><<<ggrid, blk, 0, stream>>>(
        Amsg, nullptr, Bp, 32768 + 16384, gcn_b, 128, Pa,
        ln_g, ln_b, 128, FLAG, Pb, HBa);

    // layer 2 (permute via node_map[0], index-composed into CSR1):
    // Amsg = agg1(HBa)+HBa[map0] ; Pa = Amsg@w2+b2+Pb[map0]
    agg_msg_kernel<true><<<agrid, blk, 0, stream>>>(rp1, ei1, HBa, node_map, Amsg);
    conv_gemm_kernel<true, true, false><<<ggrid, blk, 0, stream>>>(
        Amsg, node_map, Bp, 32768 + 2 * 16384, gcn_b, 256, Pb,
        ln_g, ln_b, 256, FLAG, Pa, nullptr);

    // final head: Pa[node_map[1][final_map[i]]] -> LN(ln2) -> pred -> log_softmax
    final_head_kernel<<<NOUT_D, dim3(64), 0, stream>>>(
        Pa, node_map + N_NODES, fmap, ln_g, ln_b, 256, pred_w, pred_b, FLAG,
        (void*)d_out);
}